// Round 12
// baseline (252.182 us; speedup 1.0000x reference)
//
#include <hip/hip_runtime.h>
#include <cstdint>
#include <cstddef>

typedef unsigned int u32;
typedef unsigned short u16;
typedef __attribute__((ext_vector_type(8))) short bf16x8;   // 8 bf16 = 4 VGPR
typedef __attribute__((ext_vector_type(4))) float f32x4;

#define DEV __device__ __forceinline__

DEV u16 f2b(float f){ u32 x = __float_as_uint(f); x += 0x7fffu + ((x>>16)&1u); return (u16)(x>>16); }
DEV u32 pk2(float a, float b){
  u32 r;
  asm("v_cvt_pk_bf16_f32 %0, %1, %2" : "=v"(r) : "v"(a), "v"(b));
  return r;
}

DEV void gll16(const void* g, void* l){
  __builtin_amdgcn_global_load_lds((const __attribute__((address_space(1))) u32*)g,
                                   (__attribute__((address_space(3))) u32*)l, 16, 0, 0);
}

// token row -> (window, in-window index);  H=W=D=32, g=8
DEV void win_n(int r, int& win, int& n){
  int d_ = r & 31, w_ = (r>>5)&31, h_ = r>>10;
  win = ((h_>>3)<<4) | ((w_>>3)<<2) | (d_>>3);
  n   = ((h_&7)<<6)  | ((w_&7)<<3)  | (d_&7);
}
// window-order row -> token row
DEV int tok_of(int r){
  int win = r>>9, nn = r&511;
  int bh = win>>4, bw=(win>>2)&3, bd=win&3;
  int ih = nn>>6,  iw=(nn>>3)&7,  id=nn&7;
  return ((bh*8+ih)<<10) | ((bw*8+iw)<<5) | (bd*8+id);
}

// ---------------- small prep kernels ----------------

// all four weight transposes in one dispatch: dst bf16 [N][K] = transpose(src fp32 [K][N])
__global__ void wtrall_k(const float* __restrict__ qkv_w, const float* __restrict__ proj_w,
                         const float* __restrict__ fc1_w, const float* __restrict__ fc2_w,
                         u16* __restrict__ qkvT, u16* __restrict__ projT,
                         u16* __restrict__ fc1T, u16* __restrict__ fc2T){
  int f = blockIdx.x*256 + threadIdx.x;   // 786432 total
  const float* w; u16* wt; int g; bool k10 = false; int N;
  if (f < 196608)      { w=qkv_w;  wt=qkvT;  g=f;        N=768;  }
  else if (f < 262144) { w=proj_w; wt=projT; g=f-196608; N=256;  }
  else if (f < 524288) { w=fc1_w;  wt=fc1T;  g=f-262144; N=1024; }
  else                 { w=fc2_w;  wt=fc2T;  g=f-524288; N=256;  k10=true; }
  int n = k10 ? (g>>10) : (g>>8);
  int k = k10 ? (g&1023) : (g&255);
  wt[g] = f2b(w[(size_t)k*N + n]);
}

// position-bias MLP: one thread per table row (3375 rows); emits f32 per-head tables
// scaled by log2(e) so attention softmax can run in exp2 domain.
template<int NOUT>
DEV void pstage(float* v, const float* g, const float* b, const float* W, const float* bb){
  float m = 0.f;
  #pragma unroll
  for (int i=0;i<16;i++) m += v[i];
  m *= 0.0625f;
  float q = 0.f;
  #pragma unroll
  for (int i=0;i<16;i++){ float d=v[i]-m; q += d*d; }
  float rs = rsqrtf(q*0.0625f + 1e-5f);
  float u[16];
  #pragma unroll
  for (int i=0;i<16;i++){ float t = (v[i]-m)*rs*g[i] + b[i]; u[i] = t>0.f?t:0.f; }
  #pragma unroll
  for (int o=0;o<NOUT;o++){
    float s = bb[o];
    #pragma unroll
    for (int kk=0;kk<16;kk++) s += u[kk]*W[kk*NOUT+o];
    v[o] = s;
  }
}

__global__ void posmlp_k(const float* pp_w, const float* pp_b,
                         const float* g1, const float* b1, const float* w1, const float* bb1,
                         const float* g2, const float* b2, const float* w2, const float* bb2,
                         const float* g3, const float* b3, const float* w3, const float* bb3,
                         float* __restrict__ posb){
  int i = blockIdx.x*256 + threadIdx.x;
  if (i >= 3375) return;
  int t = i;
  int bd = t % 15; t /= 15;
  int bw = t % 15; t /= 15;
  int bh = t;
  float fh = (float)(bh-7), fw = (float)(bw-7), fd = (float)(bd-7);
  float v[16];
  #pragma unroll
  for (int o=0;o<16;o++) v[o] = fh*pp_w[o] + fw*pp_w[16+o] + fd*pp_w[32+o] + pp_b[o];
  pstage<16>(v, g1,b1,w1,bb1);
  pstage<16>(v, g2,b2,w2,bb2);
  pstage<8> (v, g3,b3,w3,bb3);
  #pragma unroll
  for (int h=0;h<8;h++) posb[(size_t)h*3376 + i] = v[h] * 1.4426950408889634f;
}

// ---------------- GEMM params ----------------
struct GemmP {
  const u16* A;          // bf16 A (STG==3 gather source)
  const float* Af32;     // fp32 A (STG 1/2)
  const float* lng; const float* lnb;   // LN gamma/beta (STG==1)
  const u16* Bt;
  int K;
  const float* bvec;
  float scale;
  const float* add32;
  float* out32;
  u16* out16;
  u16* out16b;
};

// shared epilogue: D layout col=lane&15, row=(lane>>4)*4+v  [verified m89]
template<int MODE>
DEV void epi(const GemmP& p, int r, int c, float val){
  if constexpr (MODE==0){           // Q: (val+b)*scale -> Q[win*8+h][n][d]
    float qv = (val + p.bvec[c]) * p.scale;
    int win, n; win_n(r, win, n);
    int hh = c>>5, dd = c&31;
    p.out16[((size_t)((win*8+hh)*512 + n)<<5) + dd] = f2b(qv);
  } else if constexpr (MODE==1){    // K (c<256) / V (c>=256), MFMA fragment layout
    float ov = val + p.bvec[c];
    int win, n; win_n(r, win, n);
    int cc = c & 255;
    int hh = cc>>5, dd = cc&31;
    size_t base = (size_t)(win*8+hh)*16384;
    if (c < 256){
      int nc = n>>4, ln2 = ((dd>>3)<<4)|(n&15), jj = dd&7;
      p.out16[base + (size_t)(nc*64+ln2)*8 + jj] = f2b(ov);
    } else {
      int fi = ((n>>5)<<1) | (dd>>4);
      int ln2 = (((n>>3)&3)<<4)|(dd&15), jj = n&7;
      p.out16b[base + (size_t)(fi*64+ln2)*8 + jj] = f2b(ov);
    }
  } else if constexpr (MODE==2){    // proj + x residual, window row -> token row
    int l = tok_of(r);
    size_t o = (size_t)l*256 + c;
    p.out32[o] = val + p.bvec[c] + p.add32[o];
  } else if constexpr (MODE==3){    // fc1 + fast tanh-GELU (<=1e-3 abs err vs exact erf)
    float u = val + p.bvec[c];
    float e = exp2f(u*(2.3022083f + 0.1029437f*u*u));
    float ge = u*e*__builtin_amdgcn_rcpf(e+1.f);
    p.out16[(size_t)r*1024 + c] = f2b(ge);
  } else {                          // fc2 + residual -> fp32 out
    size_t o = (size_t)r*256 + c;
    p.out32[o] = val + p.bvec[c] + p.add32[o];
  }
}

// ---------------- A-in-registers GEMM (K=256) ----------------------------------
// 64-row m-tile. A panel transposed through LDS ONCE (aliased region), then held in
// areg[2][8] (64 VGPR/lane, compile-time kt indexing). Per k-step LDS traffic is
// B-only: 2 x ds_read_b128 (2KB) per 4 MFMA -> MFMA-bound (was 4KB/4MFMA = LDS-bound).
// B streamed via 3-buffer ring staged 2 ahead, counted vmcnt. LDS total 32KB.
// STG: 1 = A fp32 + fused LayerNorm; 2 = A fp32 convert; 3 = A bf16 gather (attnF).
template<int MODE, int STG, int NT>
__global__ __launch_bounds__(512, 2)
void gemmA_k(GemmP p){
  __shared__ u16 smem[16384];   // 32KB: A-stage in prologue, then B-ring 3x8KB
  const int tid = threadIdx.x;
  const int wid = tid>>6, lane = tid&63;
  const int lr = lane&15, lg = lane>>4;
  const int m0 = blockIdx.x*64;
  const int wm = (wid>>2)*32, wn = (wid&3)*32;
  const int T = NT*8;
  const f32x4 z4 = {0.f,0.f,0.f,0.f};

  // --- prologue: A panel -> frag layout in smem
  if constexpr (STG==3){
    #pragma unroll
    for (int it=0; it<4; ++it){
      int f = it*8 + wid;
      int rt = f>>3, kt = f&7;
      int row = m0 + rt*16 + lr;
      gll16(p.A + ((size_t)((row>>9)*8 + kt)*512 + (row&511))*32 + lg*8,
            (char*)smem + f*1024 + lane*16);
    }
    asm volatile("s_waitcnt vmcnt(0)" ::: "memory");
    __builtin_amdgcn_s_barrier();
  } else {
    const int row = wid*8 + (lane>>3);     // 0..63 within tile
    const int sub = lane&7;
    const float* src = p.Af32 + (size_t)(m0+row)*256;
    float xv[32];
    #pragma unroll
    for (int j=0;j<8;j++){
      float4 v = *(const float4*)(src + j*32 + sub*4);
      xv[j*4+0]=v.x; xv[j*4+1]=v.y; xv[j*4+2]=v.z; xv[j*4+3]=v.w;
    }
    float mu=0.f, rs=1.f;
    if constexpr (STG==1){
      float s=0.f;
      #pragma unroll
      for (int i2=0;i2<32;i2++) s += xv[i2];
      s += __shfl_xor(s,1); s += __shfl_xor(s,2); s += __shfl_xor(s,4);
      mu = s*(1.f/256.f);
      float q2=0.f;
      #pragma unroll
      for (int i2=0;i2<32;i2++){ float d=xv[i2]-mu; q2 += d*d; }
      q2 += __shfl_xor(q2,1); q2 += __shfl_xor(q2,2); q2 += __shfl_xor(q2,4);
      rs = rsqrtf(q2*(1.f/256.f) + 1e-5f);
    }
    const int rt = wid>>1, q = (wid&1)*8 + (lane>>3);
    #pragma unroll
    for (int j=0;j<8;j++){
      float o0,o1,o2,o3;
      if constexpr (STG==1){
        float4 gg = *(const float4*)(p.lng + j*32 + sub*4);
        float4 bb = *(const float4*)(p.lnb + j*32 + sub*4);
        o0=(xv[j*4+0]-mu)*rs*gg.x+bb.x; o1=(xv[j*4+1]-mu)*rs*gg.y+bb.y;
        o2=(xv[j*4+2]-mu)*rs*gg.z+bb.z; o3=(xv[j*4+3]-mu)*rs*gg.w+bb.w;
      } else {
        o0=xv[j*4+0]; o1=xv[j*4+1]; o2=xv[j*4+2]; o3=xv[j*4+3];
      }
      int f = rt*8 + j;
      *(uint2*)((char*)smem + f*1024 + (sub>>1)*256 + q*16 + (sub&1)*8)
          = make_uint2((u32)f2b(o0) | ((u32)f2b(o1)<<16),
                       (u32)f2b(o2) | ((u32)f2b(o3)<<16));
    }
    asm volatile("s_waitcnt lgkmcnt(0)" ::: "memory");
    __builtin_amdgcn_s_barrier();
  }
  // A frags -> registers (compile-time indexed: rule-20 safe)
  bf16x8 areg[2][8];
  #pragma unroll
  for (int i=0;i<2;i++)
    #pragma unroll
    for (int kt=0;kt<8;kt++){
      int f = ((wid>>2)*2 + i)*8 + kt;
      areg[i][kt] = *(const bf16x8*)((const char*)smem + f*1024 + lane*16);
    }
  asm volatile("s_waitcnt lgkmcnt(0)" ::: "memory");
  __builtin_amdgcn_s_barrier();     // all reads done before ring overwrites

  u16* lB = smem;                   // 3 bufs x 8KB, aliases the dead A-stage
  auto stageB = [&](int buf, int t){
    int j = t>>3, kt = t&7;
    gll16(p.Bt + (size_t)(j*128 + wid*16 + lr)*256 + kt*32 + lg*8,
          (char*)lB + buf*8192 + wid*1024 + lane*16);
  };
  stageB(0, 0);
  if (T > 1) stageB(1, 1);

  constexpr int EPIW = (MODE==2) ? 33 : 17;   // epilogue ops + 1 stage in flight
  f32x4 acc[2][2];
  #pragma unroll
  for (int i=0;i<2;i++){ acc[i][0]=z4; acc[i][1]=z4; }

  int cur = 0, stg = 2, t = 0;
  for (int j=0; j<NT; ++j){
    #pragma unroll
    for (int kt=0; kt<8; ++kt, ++t){
      if (t+1 >= T)        asm volatile("s_waitcnt vmcnt(0)" ::: "memory");
      else if (kt==0 && t) asm volatile("s_waitcnt vmcnt(%0)" :: "i"(EPIW) : "memory");
      else                 asm volatile("s_waitcnt vmcnt(1)" ::: "memory");
      __builtin_amdgcn_s_barrier();
      __builtin_amdgcn_sched_barrier(0);
      bf16x8 bfr[2];
      #pragma unroll
      for (int jj=0;jj<2;jj++)
        bfr[jj] = *(const bf16x8*)((const char*)lB + cur*8192 + ((wid&3)*2+jj)*1024 + lane*16);
      #pragma unroll
      for (int i=0;i<2;i++)
        #pragma unroll
        for (int jj=0;jj<2;jj++)
          acc[i][jj] = __builtin_amdgcn_mfma_f32_16x16x32_bf16(areg[i][kt], bfr[jj], acc[i][jj], 0,0,0);
      __builtin_amdgcn_sched_barrier(0);
      if (kt == 7){
        int n0 = j*128;
        #pragma unroll
        for (int i=0;i<2;i++)
          #pragma unroll
          for (int jj=0;jj<2;jj++){
            #pragma unroll
            for (int v=0;v<4;v++)
              epi<MODE>(p, m0 + wm + i*16 + lg*4 + v, n0 + wn + jj*16 + lr, acc[i][jj][v]);
            acc[i][jj] = z4;
          }
      }
      if (t+2 < T) stageB(stg, t+2);
      cur = (cur==2)?0:cur+1;
      stg = (stg==2)?0:stg+1;
    }
  }
}

// ---------------- fc2 GEMM (K=1024, N=256): 512 threads, n-resident ----------------
__global__ __launch_bounds__(512, 2)
void gemmW_k(GemmP p){
  __shared__ u16 lA[3][2048];   // 4 frags/buf
  __shared__ u16 lB[3][8192];   // 16 frags/buf
  const int tid = threadIdx.x;
  const int wid = tid>>6, lane = tid&63;
  const int lr = lane&15, lg = lane>>4;
  const int m0 = blockIdx.x*64;
  const int wm = (wid>>2)*32, wn = (wid&3)*64;
  const f32x4 z4 = {0.f,0.f,0.f,0.f};

  auto stage = [&](int buf, int kt){
    // A: half-fragment per wave (lanes 0-31 active)
    {
      int f = wid>>1, half = wid&1;
      if (lane < 32){
        int lg2 = half*2 + (lane>>4);
        gll16(p.A + (size_t)(m0 + f*16 + (lane&15))*1024 + kt*32 + lg2*8,
              (char*)lA[buf] + f*1024 + half*512 + lane*16);
      }
    }
    #pragma unroll
    for (int r=0;r<2;r++){
      int fb = wid*2 + r;
      gll16(p.Bt + (size_t)(fb*16 + lr)*1024 + kt*32 + lg*8,
            (char*)lB[buf] + fb*1024 + lane*16);
    }
  };
  stage(0, 0);
  stage(1, 1);

  f32x4 acc[2][4];
  #pragma unroll
  for (int i=0;i<2;i++)
    #pragma unroll
    for (int j=0;j<4;j++) acc[i][j] = z4;

  int cur = 0, stg = 2;
  for (int kt=0; kt<32; ++kt){
    if (kt+1 < 32) asm volatile("s_waitcnt vmcnt(3)" ::: "memory");
    else           asm volatile("s_waitcnt vmcnt(0)" ::: "memory");
    __builtin_amdgcn_s_barrier();
    __builtin_amdgcn_sched_barrier(0);
    bf16x8 af[2], bfr[4];
    #pragma unroll
    for (int i=0;i<2;i++){
      int fA = (wid>>2)*2 + i;
      af[i] = *(const bf16x8*)((const char*)lA[cur] + fA*1024 + lane*16);
    }
    #pragma unroll
    for (int j=0;j<4;j++){
      int fB = (wid&3)*4 + j;
      bfr[j] = *(const bf16x8*)((const char*)lB[cur] + fB*1024 + lane*16);
    }
    #pragma unroll
    for (int i=0;i<2;i++)
      #pragma unroll
      for (int j=0;j<4;j++)
        acc[i][j] = __builtin_amdgcn_mfma_f32_16x16x32_bf16(af[i], bfr[j], acc[i][j], 0,0,0);
    __builtin_amdgcn_sched_barrier(0);
    if (kt+2 < 32) stage(stg, kt+2);
    cur = (cur==2)?0:cur+1;
    stg = (stg==2)?0:stg+1;
  }

  #pragma unroll
  for (int i=0;i<2;i++)
    #pragma unroll
    for (int j=0;j<4;j++)
      #pragma unroll
      for (int v=0;v<4;v++)
        epi<4>(p, m0 + wm + i*16 + lg*4 + v, wn + j*16 + lr, acc[i][j][v]);
}

// ---------------- attention: one block per (window, head), 8 waves, 2-phase ----------------
// exp2-domain softmax, fixed reference (no max pass — scores bounded for this problem).
// Bias is fed through the QK^T MFMA's C operand (no separate v_add pass).
// Row-sum via ones-MFMA: normalizer lands in the lane's own row slot, no shuffles.
__global__ __launch_bounds__(512, 2)
void attn_k(const u16* __restrict__ Q, const u16* __restrict__ Kf,
            const u16* __restrict__ Vf, const float* __restrict__ posb,
            u16* __restrict__ outF){
  __shared__ u16 lK[16384];      // 32 frags x 1KB, fragment order
  __shared__ u16 lV[16384];      // 32 frags x 1KB (16 kc x 2 dblk)
  __shared__ float lPf[3392];    // pos table f32 (x log2e)
  const int bid = blockIdx.x;
  const int hh = bid&7;
  const int tid = threadIdx.x, wid = tid>>6, lane = tid&63;
  const int lr = lane&15, lg = lane>>4;
  const u16* Kb = Kf + (size_t)bid*16384;
  const u16* Vb = Vf + (size_t)bid*16384;
  const u16* Qb = Q  + (size_t)bid*16384;
  #pragma unroll
  for (int r=0;r<4;r++){
    int off = (r*512 + tid)*16;
    gll16((const char*)Kb + off, (char*)lK + off);
    gll16((const char*)Vb + off, (char*)lV + off);
  }
  const float* ptab = posb + (size_t)hh*3376;
  for (int t=tid; t<3375; t+=512) lPf[t] = ptab[t];
  __syncthreads();
  const f32x4 z4 = {0.f,0.f,0.f,0.f};
  const bf16x8 ones = {(short)0x3F80,(short)0x3F80,(short)0x3F80,(short)0x3F80,
                       (short)0x3F80,(short)0x3F80,(short)0x3F80,(short)0x3F80};

  for (int ch=0; ch<4; ++ch){
    const int r0 = wid*64 + ch*16;
    const int q  = r0 + lr;
    // bias index base: idx(nc,v) = Ab - (nc>>2)*225 - (nc&3)*30 - v
    const int Ab = (q>>6)*225 + ((q>>3)&7)*15 + (q&7) + 1687 - (lg>>1)*15 - (lg&1)*4;
    bf16x8 qf = *(const bf16x8*)(Qb + (size_t)q*32 + lg*8);
    f32x4 o0 = z4, o1 = z4, as_ = z4;
    #pragma unroll
    for (int ph=0; ph<2; ++ph){
      // S^T frags with bias pre-loaded as the MFMA C operand (exp2 domain)
      f32x4 sf[16];
      __builtin_amdgcn_s_setprio(1);
      #pragma unroll
      for (int i=0;i<16;i++){
        int nc = ph*16 + i;
        const float* bp = lPf + (Ab - (nc>>2)*225 - (nc&3)*30 - 3);
        f32x4 c; c[0]=bp[3]; c[1]=bp[2]; c[2]=bp[1]; c[3]=bp[0];
        bf16x8 kf = *(const bf16x8*)&lK[(nc*64 + lane)*8];
        sf[i] = __builtin_amdgcn_mfma_f32_16x16x32_bf16(kf, qf, c, 0,0,0);
      }
      __builtin_amdgcn_s_setprio(0);
      // P = exp2(S)
      #pragma unroll
      for (int i=0;i<16;i++){
        sf[i][0] = exp2f(sf[i][0]);
        sf[i][1] = exp2f(sf[i][1]);
        sf[i][2] = exp2f(sf[i][2]);
        sf[i][3] = exp2f(sf[i][3]);
      }
      // PV + ones-MFMA rowsum over this half's 8 kc blocks
      #pragma unroll
      for (int kc=0;kc<8;kc++){
        u32 a0 = pk2(sf[2*kc  ][0], sf[2*kc  ][1]);
        u32 a1 = pk2(sf[2*kc  ][2], sf[2*kc  ][3]);
        u32 b0 = pk2(sf[2*kc+1][0], sf[2*kc+1][1]);
        u32 b1 = pk2(sf[2*kc+1][2], sf[2*kc+1][3]);
        asm("v_permlane32_swap_b32 %0, %1" : "+v"(a0), "+v"(b0));
        asm("v_permlane16_swap_b32 %0, %1" : "+v"(a0), "+v"(b0));  // a0=T0, b0=T2
        asm("v_permlane32_swap_b32 %0, %1" : "+v"(a1), "+v"(b1));
        asm("v_permlane16_swap_b32 %0, %1" : "+v"(a1), "+v"(b1));  // a1=T1, b1=T3
        bf16x8 pf;
        ((u32*)&pf)[0]=a0; ((u32*)&pf)[1]=a1; ((u32*)&pf)[2]=b0; ((u32*)&pf)[3]=b1;
        int kcg = ph*8 + kc;
        bf16x8 v0 = *(const bf16x8*)&lV[(size_t)((kcg*2+0)*64 + lane)*8];
        bf16x8 v1 = *(const bf16x8*)&lV[(size_t)((kcg*2+1)*64 + lane)*8];
        __builtin_amdgcn_s_setprio(1);
        o0  = __builtin_amdgcn_mfma_f32_16x16x32_bf16(pf, v0, o0, 0,0,0);
        o1  = __builtin_amdgcn_mfma_f32_16x16x32_bf16(pf, v1, o1, 0,0,0);
        as_ = __builtin_amdgcn_mfma_f32_16x16x32_bf16(pf, ones, as_, 0,0,0);
        __builtin_amdgcn_s_setprio(0);
      }
    }
    #pragma unroll
    for (int v=0;v<4;v++){
      float inv = 1.0f / as_[v];          // rowsum already in this lane's row slot
      int n = r0 + lg*4 + v;
      size_t base = ((size_t)bid*512 + n)*32;
      outF[base + lr]      = f2b(o0[v]*inv);
      outF[base + 16 + lr] = f2b(o1[v]*inv);
    }
  }
}

// ---------------- host launch ----------------
extern "C" void kernel_launch(void* const* d_in, const int* in_sizes, int n_in,
                              void* d_out, int out_size, void* d_ws, size_t ws_size,
                              hipStream_t stream){
  const float* x      = (const float*)d_in[0];
  const float* y      = (const float*)d_in[1];
  const float* n1_g   = (const float*)d_in[2];
  const float* n1_b   = (const float*)d_in[3];
  const float* qkv_w  = (const float*)d_in[4];
  const float* qkv_b  = (const float*)d_in[5];
  const float* pp_w   = (const float*)d_in[6];
  const float* pp_b   = (const float*)d_in[7];
  const float* p1_lng = (const float*)d_in[8];
  const float* p1_lnb = (const float*)d_in[9];
  const float* p1_w   = (const float*)d_in[10];
  const float* p1_b   = (const float*)d_in[11];
  const float* p2_lng = (const float*)d_in[12];
  const float* p2_lnb = (const float*)d_in[13];
  const float* p2_w   = (const float*)d_in[14];
  const float* p2_b   = (const float*)d_in[15];
  const float* p3_lng = (const float*)d_in[16];
  const float* p3_lnb = (const float*)d_in[17];
  const float* p3_w   = (const float*)d_in[18];
  const float* p3_b   = (const float*)d_in[19];
  const float* proj_w = (const float*)d_in[20];
  const float* proj_b = (const float*)d_in[21];
  const float* n2_g   = (const float*)d_in[22];
  const float* n2_b   = (const float*)d_in[23];
  const float* fc1_w  = (const float*)d_in[24];
  const float* fc1_b  = (const float*)d_in[25];
  const float* fc2_w  = (const float*)d_in[26];
  const float* fc2_b  = (const float*)d_in[27];
  float* out = (float*)d_out;
  char* ws = (char*)d_ws;

  // workspace layout (bytes)
  u16*   qkvT  = (u16*)  (ws + 0);          // [768][256] bf16
  u16*   projT = (u16*)  (ws + 393216);     // [256][256]
  u16*   fc1T  = (u16*)  (ws + 524288);     // [1024][256]
  u16*   fc2T  = (u16*)  (ws + 1048576);    // [256][1024]
  float* posb  = (float*)(ws + 1572864);    // [8][3376] f32 per-head pos tables (x log2e)
  u16*   hbuf  = (u16*)  (ws + 5898240);    // MLP hidden [32768][1024] bf16 (67 MB)
  u16*   Qb    = (u16*)  (ws + 39452672);   // [512 bh][512 n][32 d]   (dead by fc1)
  u16*   Kfb   = (u16*)  (ws + 56229888);   // [512 bh][32 frag][64 lane][8]  (dead by fc1)
  u16*   Vfb   = (u16*)  (ws + 73007104);   // [512 bh][32 frag][64 lane][8]  (dead by proj)
  u16*   attnF = (u16*)  (ws + 89784320);   // [512 bh][512 n][32 d] block-contiguous
  float* xres  = (float*)(ws + 106561536);  // [32768][256] fp32   (end 140,115,968)

  wtrall_k<<<3072,256,0,stream>>>(qkv_w, proj_w, fc1_w, fc2_w, qkvT, projT, fc1T, fc2T);
  posmlp_k<<<14,256,0,stream>>>(pp_w, pp_b,
                                p1_lng,p1_lnb,p1_w,p1_b,
                                p2_lng,p2_lnb,p2_w,p2_b,
                                p3_lng,p3_lnb,p3_w,p3_b, posb);

  GemmP pq; pq.A=nullptr; pq.Af32=x; pq.lng=n1_g; pq.lnb=n1_b;
  pq.Bt=qkvT; pq.K=256; pq.bvec=qkv_b;
  pq.scale=0.17677669529663687f*1.4426950408889634f;  // hd^-0.5 * log2(e)
  pq.add32=nullptr; pq.out32=nullptr; pq.out16=Qb; pq.out16b=nullptr;
  gemmA_k<0,1,2><<<512,512,0,stream>>>(pq);

  GemmP pkv; pkv.A=nullptr; pkv.Af32=y; pkv.lng=nullptr; pkv.lnb=nullptr;
  pkv.Bt=qkvT + 256*256; pkv.K=256; pkv.bvec=qkv_b + 256;
  pkv.scale=1.f; pkv.add32=nullptr; pkv.out32=nullptr; pkv.out16=Kfb; pkv.out16b=Vfb;
  gemmA_k<1,2,4><<<512,512,0,stream>>>(pkv);

  attn_k<<<512,512,0,stream>>>(Qb, Kfb, Vfb, posb, attnF);

  GemmP pp; pp.A=attnF; pp.Af32=nullptr; pp.lng=nullptr; pp.lnb=nullptr;
  pp.Bt=projT; pp.K=256; pp.bvec=proj_b;
  pp.scale=1.f; pp.add32=x; pp.out32=xres; pp.out16=nullptr; pp.out16b=nullptr;
  gemmA_k<2,3,2><<<512,512,0,stream>>>(pp);

  GemmP pf1; pf1.A=nullptr; pf1.Af32=xres; pf1.lng=n2_g; pf1.lnb=n2_b;
  pf1.Bt=fc1T; pf1.K=256; pf1.bvec=fc1_b;
  pf1.scale=1.f; pf1.add32=nullptr; pf1.out32=nullptr; pf1.out16=hbuf; pf1.out16b=nullptr;
  gemmA_k<3,1,8><<<512,512,0,stream>>>(pf1);

  GemmP pf2; pf2.A=hbuf; pf2.Af32=nullptr; pf2.lng=nullptr; pf2.lnb=nullptr;
  pf2.Bt=fc2T; pf2.K=1024; pf2.bvec=fc2_b;
  pf2.scale=1.f; pf2.add32=xres; pf2.out32=out; pf2.out16=nullptr; pf2.out16b=nullptr;
  gemmW_k<<<512,512,0,stream>>>(pf2);
}

// Round 13
// 248.538 us; speedup vs baseline: 1.0147x; 1.0147x over previous
//
#include <hip/hip_runtime.h>
#include <cstdint>
#include <cstddef>

typedef unsigned int u32;
typedef unsigned short u16;
typedef __attribute__((ext_vector_type(8))) short bf16x8;   // 8 bf16 = 4 VGPR
typedef __attribute__((ext_vector_type(4))) float f32x4;

#define DEV __device__ __forceinline__

DEV u16 f2b(float f){ u32 x = __float_as_uint(f); x += 0x7fffu + ((x>>16)&1u); return (u16)(x>>16); }
DEV u32 pk2(float a, float b){
  u32 r;
  asm("v_cvt_pk_bf16_f32 %0, %1, %2" : "=v"(r) : "v"(a), "v"(b));
  return r;
}

DEV void gll16(const void* g, void* l){
  __builtin_amdgcn_global_load_lds((const __attribute__((address_space(1))) u32*)g,
                                   (__attribute__((address_space(3))) u32*)l, 16, 0, 0);
}

// token row -> (window, in-window index);  H=W=D=32, g=8
DEV void win_n(int r, int& win, int& n){
  int d_ = r & 31, w_ = (r>>5)&31, h_ = r>>10;
  win = ((h_>>3)<<4) | ((w_>>3)<<2) | (d_>>3);
  n   = ((h_&7)<<6)  | ((w_&7)<<3)  | (d_&7);
}
// window-order row -> token row
DEV int tok_of(int r){
  int win = r>>9, nn = r&511;
  int bh = win>>4, bw=(win>>2)&3, bd=win&3;
  int ih = nn>>6,  iw=(nn>>3)&7,  id=nn&7;
  return ((bh*8+ih)<<10) | ((bw*8+iw)<<5) | (bd*8+id);
}

// ---------------- small prep kernels ----------------

// all four weight transposes in one dispatch: dst bf16 [N][K] = transpose(src fp32 [K][N])
__global__ void wtrall_k(const float* __restrict__ qkv_w, const float* __restrict__ proj_w,
                         const float* __restrict__ fc1_w, const float* __restrict__ fc2_w,
                         u16* __restrict__ qkvT, u16* __restrict__ projT,
                         u16* __restrict__ fc1T, u16* __restrict__ fc2T){
  int f = blockIdx.x*256 + threadIdx.x;   // 786432 total
  const float* w; u16* wt; int g; bool k10 = false; int N;
  if (f < 196608)      { w=qkv_w;  wt=qkvT;  g=f;        N=768;  }
  else if (f < 262144) { w=proj_w; wt=projT; g=f-196608; N=256;  }
  else if (f < 524288) { w=fc1_w;  wt=fc1T;  g=f-262144; N=1024; }
  else                 { w=fc2_w;  wt=fc2T;  g=f-524288; N=256;  k10=true; }
  int n = k10 ? (g>>10) : (g>>8);
  int k = k10 ? (g&1023) : (g&255);
  wt[g] = f2b(w[(size_t)k*N + n]);
}

// position-bias MLP: one thread per table row (3375 rows); emits f32 per-head tables
// scaled by log2(e) so attention softmax can run in exp2 domain.
template<int NOUT>
DEV void pstage(float* v, const float* g, const float* b, const float* W, const float* bb){
  float m = 0.f;
  #pragma unroll
  for (int i=0;i<16;i++) m += v[i];
  m *= 0.0625f;
  float q = 0.f;
  #pragma unroll
  for (int i=0;i<16;i++){ float d=v[i]-m; q += d*d; }
  float rs = rsqrtf(q*0.0625f + 1e-5f);
  float u[16];
  #pragma unroll
  for (int i=0;i<16;i++){ float t = (v[i]-m)*rs*g[i] + b[i]; u[i] = t>0.f?t:0.f; }
  #pragma unroll
  for (int o=0;o<NOUT;o++){
    float s = bb[o];
    #pragma unroll
    for (int kk=0;kk<16;kk++) s += u[kk]*W[kk*NOUT+o];
    v[o] = s;
  }
}

__global__ void posmlp_k(const float* pp_w, const float* pp_b,
                         const float* g1, const float* b1, const float* w1, const float* bb1,
                         const float* g2, const float* b2, const float* w2, const float* bb2,
                         const float* g3, const float* b3, const float* w3, const float* bb3,
                         float* __restrict__ posb){
  int i = blockIdx.x*256 + threadIdx.x;
  if (i >= 3375) return;
  int t = i;
  int bd = t % 15; t /= 15;
  int bw = t % 15; t /= 15;
  int bh = t;
  float fh = (float)(bh-7), fw = (float)(bw-7), fd = (float)(bd-7);
  float v[16];
  #pragma unroll
  for (int o=0;o<16;o++) v[o] = fh*pp_w[o] + fw*pp_w[16+o] + fd*pp_w[32+o] + pp_b[o];
  pstage<16>(v, g1,b1,w1,bb1);
  pstage<16>(v, g2,b2,w2,bb2);
  pstage<8> (v, g3,b3,w3,bb3);
  #pragma unroll
  for (int h=0;h<8;h++) posb[(size_t)h*3376 + i] = v[h] * 1.4426950408889634f;
}

// ---------------- GEMM params ----------------
struct GemmP {
  const u16* A;          // bf16 A (STG==3 gather source)
  const float* Af32;     // fp32 A (STG 1/2)
  const float* lng; const float* lnb;   // LN gamma/beta (STG==1)
  const u16* Bt;
  int K;
  const float* bvec;
  float scale;
  const float* add32;
  float* out32;
  u16* out16;
  u16* out16b;
};

// shared epilogue: D layout col=lane&15, row=(lane>>4)*4+v  [verified m89]
template<int MODE>
DEV void epi(const GemmP& p, int r, int c, float val){
  if constexpr (MODE==0){           // Q: (val+b)*scale -> Q[win*8+h][n][d]
    float qv = (val + p.bvec[c]) * p.scale;
    int win, n; win_n(r, win, n);
    int hh = c>>5, dd = c&31;
    p.out16[((size_t)((win*8+hh)*512 + n)<<5) + dd] = f2b(qv);
  } else if constexpr (MODE==1){    // K (c<256) / V (c>=256), MFMA fragment layout
    float ov = val + p.bvec[c];
    int win, n; win_n(r, win, n);
    int cc = c & 255;
    int hh = cc>>5, dd = cc&31;
    size_t base = (size_t)(win*8+hh)*16384;
    if (c < 256){
      int nc = n>>4, ln2 = ((dd>>3)<<4)|(n&15), jj = dd&7;
      p.out16[base + (size_t)(nc*64+ln2)*8 + jj] = f2b(ov);
    } else {
      int fi = ((n>>5)<<1) | (dd>>4);
      int ln2 = (((n>>3)&3)<<4)|(dd&15), jj = n&7;
      p.out16b[base + (size_t)(fi*64+ln2)*8 + jj] = f2b(ov);
    }
  } else if constexpr (MODE==2){    // proj + x residual, window row -> token row
    int l = tok_of(r);
    size_t o = (size_t)l*256 + c;
    p.out32[o] = val + p.bvec[c] + p.add32[o];
  } else if constexpr (MODE==3){    // fc1 + fast tanh-GELU (<=1e-3 abs err vs exact erf)
    float u = val + p.bvec[c];
    float e = exp2f(u*(2.3022083f + 0.1029437f*u*u));
    float ge = u*e*__builtin_amdgcn_rcpf(e+1.f);
    p.out16[(size_t)r*1024 + c] = f2b(ge);
  } else {                          // fc2 + residual -> fp32 out
    size_t o = (size_t)r*256 + c;
    p.out32[o] = val + p.bvec[c] + p.add32[o];
  }
}

// ---------------- A-in-registers GEMM (K=256) ----------------------------------
// 64-row m-tile. A panel staged through LDS once then held in areg[2][8]; per k-step
// only B streams from LDS (3-buffer ring staged 2 ahead, counted vmcnt). LDS 32KB.
// MODE1 V-tiles (n0>=256) use a transposed epilogue: pk2+permlane32/16 on the frag
// pair (acc[i][0],acc[i][1]) yields lane L = rows ((L>>4&1)*8+e) x col (wn+(L>>5)*16
// +(L&15)) = n-contiguous 8 = one 16B store per i (vs 8 scalar 2B stores).
// STG: 1 = A fp32 + fused LayerNorm; 2 = A fp32 convert; 3 = A bf16 gather (attnF).
template<int MODE, int STG, int NT>
__global__ __launch_bounds__(512, 2)
void gemmA_k(GemmP p){
  __shared__ u16 smem[16384];   // 32KB: A-stage in prologue, then B-ring 3x8KB
  const int tid = threadIdx.x;
  const int wid = tid>>6, lane = tid&63;
  const int lr = lane&15, lg = lane>>4;
  const int m0 = blockIdx.x*64;
  const int wm = (wid>>2)*32, wn = (wid&3)*32;
  const int T = NT*8;
  const f32x4 z4 = {0.f,0.f,0.f,0.f};

  // --- prologue: A panel -> frag layout in smem
  if constexpr (STG==3){
    #pragma unroll
    for (int it=0; it<4; ++it){
      int f = it*8 + wid;
      int rt = f>>3, kt = f&7;
      int row = m0 + rt*16 + lr;
      gll16(p.A + ((size_t)((row>>9)*8 + kt)*512 + (row&511))*32 + lg*8,
            (char*)smem + f*1024 + lane*16);
    }
    asm volatile("s_waitcnt vmcnt(0)" ::: "memory");
    __builtin_amdgcn_s_barrier();
  } else {
    const int row = wid*8 + (lane>>3);     // 0..63 within tile
    const int sub = lane&7;
    const float* src = p.Af32 + (size_t)(m0+row)*256;
    float xv[32];
    #pragma unroll
    for (int j=0;j<8;j++){
      float4 v = *(const float4*)(src + j*32 + sub*4);
      xv[j*4+0]=v.x; xv[j*4+1]=v.y; xv[j*4+2]=v.z; xv[j*4+3]=v.w;
    }
    float mu=0.f, rs=1.f;
    if constexpr (STG==1){
      float s=0.f;
      #pragma unroll
      for (int i2=0;i2<32;i2++) s += xv[i2];
      s += __shfl_xor(s,1); s += __shfl_xor(s,2); s += __shfl_xor(s,4);
      mu = s*(1.f/256.f);
      float q2=0.f;
      #pragma unroll
      for (int i2=0;i2<32;i2++){ float d=xv[i2]-mu; q2 += d*d; }
      q2 += __shfl_xor(q2,1); q2 += __shfl_xor(q2,2); q2 += __shfl_xor(q2,4);
      rs = rsqrtf(q2*(1.f/256.f) + 1e-5f);
    }
    const int rt = wid>>1, q = (wid&1)*8 + (lane>>3);
    #pragma unroll
    for (int j=0;j<8;j++){
      float o0,o1,o2,o3;
      if constexpr (STG==1){
        float4 gg = *(const float4*)(p.lng + j*32 + sub*4);
        float4 bb = *(const float4*)(p.lnb + j*32 + sub*4);
        o0=(xv[j*4+0]-mu)*rs*gg.x+bb.x; o1=(xv[j*4+1]-mu)*rs*gg.y+bb.y;
        o2=(xv[j*4+2]-mu)*rs*gg.z+bb.z; o3=(xv[j*4+3]-mu)*rs*gg.w+bb.w;
      } else {
        o0=xv[j*4+0]; o1=xv[j*4+1]; o2=xv[j*4+2]; o3=xv[j*4+3];
      }
      int f = rt*8 + j;
      *(uint2*)((char*)smem + f*1024 + (sub>>1)*256 + q*16 + (sub&1)*8)
          = make_uint2((u32)f2b(o0) | ((u32)f2b(o1)<<16),
                       (u32)f2b(o2) | ((u32)f2b(o3)<<16));
    }
    asm volatile("s_waitcnt lgkmcnt(0)" ::: "memory");
    __builtin_amdgcn_s_barrier();
  }
  // A frags -> registers (compile-time indexed: rule-20 safe)
  bf16x8 areg[2][8];
  #pragma unroll
  for (int i=0;i<2;i++)
    #pragma unroll
    for (int kt=0;kt<8;kt++){
      int f = ((wid>>2)*2 + i)*8 + kt;
      areg[i][kt] = *(const bf16x8*)((const char*)smem + f*1024 + lane*16);
    }
  asm volatile("s_waitcnt lgkmcnt(0)" ::: "memory");
  __builtin_amdgcn_s_barrier();     // all reads done before ring overwrites

  u16* lB = smem;                   // 3 bufs x 8KB, aliases the dead A-stage
  auto stageB = [&](int buf, int t){
    int j = t>>3, kt = t&7;
    gll16(p.Bt + (size_t)(j*128 + wid*16 + lr)*256 + kt*32 + lg*8,
          (char*)lB + buf*8192 + wid*1024 + lane*16);
  };
  stageB(0, 0);
  if (T > 1) stageB(1, 1);

  f32x4 acc[2][2];
  #pragma unroll
  for (int i=0;i<2;i++){ acc[i][0]=z4; acc[i][1]=z4; }

  int cur = 0, stg = 2, t = 0;
  for (int j=0; j<NT; ++j){
    #pragma unroll
    for (int kt=0; kt<8; ++kt, ++t){
      if (t+1 >= T){
        asm volatile("s_waitcnt vmcnt(0)" ::: "memory");
      } else if (kt==0 && t){
        if constexpr (MODE==2)       asm volatile("s_waitcnt vmcnt(33)" ::: "memory");
        else if (MODE==1 && NT==4){  // previous tile j-1: V (2-store transposed epi) iff j-1>=2
          if (j==3) asm volatile("s_waitcnt vmcnt(3)"  ::: "memory");
          else      asm volatile("s_waitcnt vmcnt(17)" ::: "memory");
        } else                       asm volatile("s_waitcnt vmcnt(17)" ::: "memory");
      } else {
        asm volatile("s_waitcnt vmcnt(1)" ::: "memory");
      }
      __builtin_amdgcn_s_barrier();
      __builtin_amdgcn_sched_barrier(0);
      bf16x8 bfr[2];
      #pragma unroll
      for (int jj=0;jj<2;jj++)
        bfr[jj] = *(const bf16x8*)((const char*)lB + cur*8192 + ((wid&3)*2+jj)*1024 + lane*16);
      #pragma unroll
      for (int i=0;i<2;i++)
        #pragma unroll
        for (int jj=0;jj<2;jj++)
          acc[i][jj] = __builtin_amdgcn_mfma_f32_16x16x32_bf16(areg[i][kt], bfr[jj], acc[i][jj], 0,0,0);
      __builtin_amdgcn_sched_barrier(0);
      if (kt == 7){
        int n0 = j*128;
        if (MODE==1 && n0 >= 256){
          // V half: transposed epilogue, one 16B store per i
          #pragma unroll
          for (int i=0;i<2;i++){
            float bb0 = p.bvec[n0+wn+lr], bb1 = p.bvec[n0+wn+16+lr];
            u32 a0 = pk2(acc[i][0][0]+bb0, acc[i][0][1]+bb0);
            u32 a1 = pk2(acc[i][0][2]+bb0, acc[i][0][3]+bb0);
            u32 b0 = pk2(acc[i][1][0]+bb1, acc[i][1][1]+bb1);
            u32 b1 = pk2(acc[i][1][2]+bb1, acc[i][1][3]+bb1);
            asm("v_permlane32_swap_b32 %0, %1" : "+v"(a0), "+v"(b0));
            asm("v_permlane16_swap_b32 %0, %1" : "+v"(a0), "+v"(b0));
            asm("v_permlane32_swap_b32 %0, %1" : "+v"(a1), "+v"(b1));
            asm("v_permlane16_swap_b32 %0, %1" : "+v"(a1), "+v"(b1));
            bf16x8 fr;
            ((u32*)&fr)[0]=a0; ((u32*)&fr)[1]=a1; ((u32*)&fr)[2]=b0; ((u32*)&fr)[3]=b1;
            int r8 = m0 + wm + i*16 + ((lane>>4)&1)*8;       // 8-token run start
            int c  = n0 + wn + ((lane>>5)&1)*16 + lr;
            int win, n; win_n(r8, win, n);
            int cc = c & 255, hhh = cc>>5, dd = cc&31;
            size_t base = (size_t)(win*8+hhh)*16384;
            int fi  = ((n>>5)<<1) | (dd>>4);
            int ln2 = (((n>>3)&3)<<4) | (dd&15);
            *(bf16x8*)(p.out16b + base + (size_t)(fi*64+ln2)*8) = fr;
            acc[i][0] = z4; acc[i][1] = z4;
          }
        } else {
          #pragma unroll
          for (int i=0;i<2;i++)
            #pragma unroll
            for (int jj=0;jj<2;jj++){
              #pragma unroll
              for (int v=0;v<4;v++)
                epi<MODE>(p, m0 + wm + i*16 + lg*4 + v, n0 + wn + jj*16 + lr, acc[i][jj][v]);
              acc[i][jj] = z4;
            }
        }
      }
      if (t+2 < T) stageB(stg, t+2);
      cur = (cur==2)?0:cur+1;
      stg = (stg==2)?0:stg+1;
    }
  }
}

// ---------------- fc2 GEMM (K=1024, N=256): 512 threads, n-resident ----------------
__global__ __launch_bounds__(512, 2)
void gemmW_k(GemmP p){
  __shared__ u16 lA[3][2048];   // 4 frags/buf
  __shared__ u16 lB[3][8192];   // 16 frags/buf
  const int tid = threadIdx.x;
  const int wid = tid>>6, lane = tid&63;
  const int lr = lane&15, lg = lane>>4;
  const int m0 = blockIdx.x*64;
  const int wm = (wid>>2)*32, wn = (wid&3)*64;
  const f32x4 z4 = {0.f,0.f,0.f,0.f};

  auto stage = [&](int buf, int kt){
    // A: half-fragment per wave (lanes 0-31 active)
    {
      int f = wid>>1, half = wid&1;
      if (lane < 32){
        int lg2 = half*2 + (lane>>4);
        gll16(p.A + (size_t)(m0 + f*16 + (lane&15))*1024 + kt*32 + lg2*8,
              (char*)lA[buf] + f*1024 + half*512 + lane*16);
      }
    }
    #pragma unroll
    for (int r=0;r<2;r++){
      int fb = wid*2 + r;
      gll16(p.Bt + (size_t)(fb*16 + lr)*1024 + kt*32 + lg*8,
            (char*)lB[buf] + fb*1024 + lane*16);
    }
  };
  stage(0, 0);
  stage(1, 1);

  f32x4 acc[2][4];
  #pragma unroll
  for (int i=0;i<2;i++)
    #pragma unroll
    for (int j=0;j<4;j++) acc[i][j] = z4;

  int cur = 0, stg = 2;
  for (int kt=0; kt<32; ++kt){
    if (kt+1 < 32) asm volatile("s_waitcnt vmcnt(3)" ::: "memory");
    else           asm volatile("s_waitcnt vmcnt(0)" ::: "memory");
    __builtin_amdgcn_s_barrier();
    __builtin_amdgcn_sched_barrier(0);
    bf16x8 af[2], bfr[4];
    #pragma unroll
    for (int i=0;i<2;i++){
      int fA = (wid>>2)*2 + i;
      af[i] = *(const bf16x8*)((const char*)lA[cur] + fA*1024 + lane*16);
    }
    #pragma unroll
    for (int j=0;j<4;j++){
      int fB = (wid&3)*4 + j;
      bfr[j] = *(const bf16x8*)((const char*)lB[cur] + fB*1024 + lane*16);
    }
    #pragma unroll
    for (int i=0;i<2;i++)
      #pragma unroll
      for (int j=0;j<4;j++)
        acc[i][j] = __builtin_amdgcn_mfma_f32_16x16x32_bf16(af[i], bfr[j], acc[i][j], 0,0,0);
    __builtin_amdgcn_sched_barrier(0);
    if (kt+2 < 32) stage(stg, kt+2);
    cur = (cur==2)?0:cur+1;
    stg = (stg==2)?0:stg+1;
  }

  #pragma unroll
  for (int i=0;i<2;i++)
    #pragma unroll
    for (int j=0;j<4;j++)
      #pragma unroll
      for (int v=0;v<4;v++)
        epi<4>(p, m0 + wm + i*16 + lg*4 + v, wn + j*16 + lr, acc[i][j][v]);
}

// ---------------- attention: one block per (window, head), 8 waves, 2-phase ----------------
// K fragments read DIRECTLY from global (L2-resident, coalesced 1KB/wave/frag):
// drops lK -> LDS 45.3KB -> 2 blocks/CU (was 77.5KB -> 1 block/CU since round 4).
// exp2-domain softmax, fixed reference; ones-MFMA rowsum (no shuffles).
__global__ __launch_bounds__(512, 2)
void attn_k(const u16* __restrict__ Q, const u16* __restrict__ Kf,
            const u16* __restrict__ Vf, const float* __restrict__ posb,
            u16* __restrict__ outF){
  __shared__ u16 lV[16384];      // 32 frags x 1KB (16 kc x 2 dblk)
  __shared__ float lPf[3392];    // pos table f32 (x log2e)
  const int bid = blockIdx.x;
  const int hh = bid&7;
  const int tid = threadIdx.x, wid = tid>>6, lane = tid&63;
  const int lr = lane&15, lg = lane>>4;
  const u16* Kb = Kf + (size_t)bid*16384;
  const u16* Vb = Vf + (size_t)bid*16384;
  const u16* Qb = Q  + (size_t)bid*16384;
  #pragma unroll
  for (int r=0;r<4;r++){
    int off = (r*512 + tid)*16;
    gll16((const char*)Vb + off, (char*)lV + off);
  }
  const float* ptab = posb + (size_t)hh*3376;
  for (int t=tid; t<3375; t+=512) lPf[t] = ptab[t];
  __syncthreads();
  const f32x4 z4 = {0.f,0.f,0.f,0.f};
  const bf16x8 ones = {(short)0x3F80,(short)0x3F80,(short)0x3F80,(short)0x3F80,
                       (short)0x3F80,(short)0x3F80,(short)0x3F80,(short)0x3F80};

  for (int ch=0; ch<4; ++ch){
    const int r0 = wid*64 + ch*16;
    const int q  = r0 + lr;
    // bias index base: idx(nc,v) = Ab - (nc>>2)*225 - (nc&3)*30 - v
    const int Ab = (q>>6)*225 + ((q>>3)&7)*15 + (q&7) + 1687 - (lg>>1)*15 - (lg&1)*4;
    bf16x8 qf = *(const bf16x8*)(Qb + (size_t)q*32 + lg*8);
    f32x4 o0 = z4, o1 = z4, as_ = z4;
    #pragma unroll
    for (int ph=0; ph<2; ++ph){
      // S^T frags: sf[i][v] = S[q][n=(ph*16+i)*16+lg*4+v]  (exp2 domain)
      f32x4 sf[16];
      __builtin_amdgcn_s_setprio(1);
      #pragma unroll
      for (int i=0;i<16;i++){
        int nc = ph*16 + i;
        bf16x8 kf = *(const bf16x8*)(Kb + (size_t)(nc*64 + lane)*8);   // global K
        sf[i] = __builtin_amdgcn_mfma_f32_16x16x32_bf16(kf, qf, z4, 0,0,0);
      }
      __builtin_amdgcn_s_setprio(0);
      // P = exp2(S + bias)
      #pragma unroll
      for (int i=0;i<16;i++){
        int nc = ph*16 + i;
        const float* bp = lPf + (Ab - (nc>>2)*225 - (nc&3)*30 - 3);
        sf[i][3] = exp2f(sf[i][3] + bp[0]);
        sf[i][2] = exp2f(sf[i][2] + bp[1]);
        sf[i][1] = exp2f(sf[i][1] + bp[2]);
        sf[i][0] = exp2f(sf[i][0] + bp[3]);
      }
      // PV + ones-MFMA rowsum over this half's 8 kc blocks
      #pragma unroll
      for (int kc=0;kc<8;kc++){
        u32 a0 = pk2(sf[2*kc  ][0], sf[2*kc  ][1]);
        u32 a1 = pk2(sf[2*kc  ][2], sf[2*kc  ][3]);
        u32 b0 = pk2(sf[2*kc+1][0], sf[2*kc+1][1]);
        u32 b1 = pk2(sf[2*kc+1][2], sf[2*kc+1][3]);
        asm("v_permlane32_swap_b32 %0, %1" : "+v"(a0), "+v"(b0));
        asm("v_permlane16_swap_b32 %0, %1" : "+v"(a0), "+v"(b0));  // a0=T0, b0=T2
        asm("v_permlane32_swap_b32 %0, %1" : "+v"(a1), "+v"(b1));
        asm("v_permlane16_swap_b32 %0, %1" : "+v"(a1), "+v"(b1));  // a1=T1, b1=T3
        bf16x8 pf;
        ((u32*)&pf)[0]=a0; ((u32*)&pf)[1]=a1; ((u32*)&pf)[2]=b0; ((u32*)&pf)[3]=b1;
        int kcg = ph*8 + kc;
        bf16x8 v0 = *(const bf16x8*)&lV[(size_t)((kcg*2+0)*64 + lane)*8];
        bf16x8 v1 = *(const bf16x8*)&lV[(size_t)((kcg*2+1)*64 + lane)*8];
        __builtin_amdgcn_s_setprio(1);
        o0  = __builtin_amdgcn_mfma_f32_16x16x32_bf16(pf, v0, o0, 0,0,0);
        o1  = __builtin_amdgcn_mfma_f32_16x16x32_bf16(pf, v1, o1, 0,0,0);
        as_ = __builtin_amdgcn_mfma_f32_16x16x32_bf16(pf, ones, as_, 0,0,0);
        __builtin_amdgcn_s_setprio(0);
      }
    }
    #pragma unroll
    for (int v=0;v<4;v++){
      float inv = 1.0f / as_[v];          // rowsum already in this lane's row slot
      int n = r0 + lg*4 + v;
      size_t base = ((size_t)bid*512 + n)*32;
      outF[base + lr]      = f2b(o0[v]*inv);
      outF[base + 16 + lr] = f2b(o1[v]*inv);
    }
  }
}

// ---------------- host launch ----------------
extern "C" void kernel_launch(void* const* d_in, const int* in_sizes, int n_in,
                              void* d_out, int out_size, void* d_ws, size_t ws_size,
                              hipStream_t stream){
  const float* x      = (const float*)d_in[0];
  const float* y      = (const float*)d_in[1];
  const float* n1_g   = (const float*)d_in[2];
  const float* n1_b   = (const float*)d_in[3];
  const float* qkv_w  = (const float*)d_in[4];
  const float* qkv_b  = (const float*)d_in[5];
  const float* pp_w   = (const float*)d_in[6];
  const float* pp_b   = (const float*)d_in[7];
  const float* p1_lng = (const float*)d_in[8];
  const float* p1_lnb = (const float*)d_in[9];
  const float* p1_w   = (const float*)d_in[10];
  const float* p1_b   = (const float*)d_in[11];
  const float* p2_lng = (const float*)d_in[12];
  const float* p2_lnb = (const float*)d_in[13];
  const float* p2_w   = (const float*)d_in[14];
  const float* p2_b   = (const float*)d_in[15];
  const float* p3_lng = (const float*)d_in[16];
  const float* p3_lnb = (const float*)d_in[17];
  const float* p3_w   = (const float*)d_in[18];
  const float* p3_b   = (const float*)d_in[19];
  const float* proj_w = (const float*)d_in[20];
  const float* proj_b = (const float*)d_in[21];
  const float* n2_g   = (const float*)d_in[22];
  const float* n2_b   = (const float*)d_in[23];
  const float* fc1_w  = (const float*)d_in[24];
  const float* fc1_b  = (const float*)d_in[25];
  const float* fc2_w  = (const float*)d_in[26];
  const float* fc2_b  = (const float*)d_in[27];
  float* out = (float*)d_out;
  char* ws = (char*)d_ws;

  // workspace layout (bytes)
  u16*   qkvT  = (u16*)  (ws + 0);          // [768][256] bf16
  u16*   projT = (u16*)  (ws + 393216);     // [256][256]
  u16*   fc1T  = (u16*)  (ws + 524288);     // [1024][256]
  u16*   fc2T  = (u16*)  (ws + 1048576);    // [256][1024]
  float* posb  = (float*)(ws + 1572864);    // [8][3376] f32 per-head pos tables (x log2e)
  u16*   hbuf  = (u16*)  (ws + 5898240);    // MLP hidden [32768][1024] bf16 (67 MB)
  u16*   Qb    = (u16*)  (ws + 39452672);   // [512 bh][512 n][32 d]   (dead by fc1)
  u16*   Kfb   = (u16*)  (ws + 56229888);   // [512 bh][32 frag][64 lane][8]  (dead by fc1)
  u16*   Vfb   = (u16*)  (ws + 73007104);   // [512 bh][32 frag][64 lane][8]  (dead by proj)
  u16*   attnF = (u16*)  (ws + 89784320);   // [512 bh][512 n][32 d] block-contiguous
  float* xres  = (float*)(ws + 106561536);  // [32768][256] fp32   (end 140,115,968)

  wtrall_k<<<3072,256,0,stream>>>(qkv_w, proj_w, fc1_w, fc2_w, qkvT, projT, fc1T, fc2T);
  posmlp_k<<<14,256,0,stream>>>(pp_w, pp_b,
                                p1_lng,p1_lnb,p1_w,p1_b,
                                p2_lng,p2_lnb,p2_w,p2_b,
                                p3_lng,p3_lnb,p3_w,p3_b, posb);

  GemmP pq; pq.A=nullptr; pq.Af32=x; pq.lng=n1_g; pq.lnb=n1_b;
  pq.Bt=qkvT; pq.K=256; pq.bvec=qkv_b;
  pq.scale=0.17677669529663687f*1.4426950408889634f;  // hd^-0.5 * log2(e)
  pq.add32=nullptr; pq.out32=nullptr; pq.out16=Qb; pq.out16b=nullptr;
  gemmA_k<0,1,2><<<512,512,0,stream>>>(pq);

  GemmP pkv; pkv.A=nullptr; pkv.Af32=y; pkv.lng=nullptr; pkv.lnb=nullptr;
  pkv.Bt=qkvT + 256*256; pkv.K=256; pkv.bvec=qkv_b + 256;
  pkv.scale=1.f; pkv.add32=nullptr; pkv.out32=nullptr; pkv.out16=Kfb; pkv.out16b=Vfb;
  gemmA_k<1,2,4><<<512,512,0,stream>>>(pkv);

  attn_k<<<512,512,0,stream>>>(Qb, Kfb, Vfb, posb, attnF);

  GemmP pp; pp.A=attnF; pp.Af32=nullptr; pp.lng=nullptr; pp.lnb=nullptr;
  pp.Bt=projT; pp.K=256; pp.bvec=proj_b;
  pp.scale=1.f; pp.add32=x; pp.out32=xres; pp.out16=nullptr; pp.out16b=nullptr;
  gemmA_k<2,3,2><<<512,512,0,stream>>>(pp);

  GemmP pf1; pf1.A=nullptr; pf1.Af32=xres; pf1.lng=n2_g; pf1.lnb=n2_b;
  pf1.Bt=fc1T; pf1.K=256; pf1.bvec=fc1_b;
  pf1.scale=1.f; pf1.add32=nullptr; pf1.out32=nullptr; pf1.out16=hbuf; pf1.out16b=nullptr;
  gemmA_k<3,1,8><<<512,512,0,stream>>>(pf1);

  GemmP pf2; pf2.A=hbuf; pf2.Af32=nullptr; pf2.lng=nullptr; pf2.lnb=nullptr;
  pf2.Bt=fc2T; pf2.K=1024; pf2.bvec=fc2_b;
  pf2.scale=1.f; pf2.add32=xres; pf2.out32=out; pf2.out16=nullptr; pf2.out16b=nullptr;
  gemmW_k<<<512,512,0,stream>>>(pf2);
}

// Round 15
// 246.564 us; speedup vs baseline: 1.0228x; 1.0080x over previous
//
#include <hip/hip_runtime.h>
#include <cstdint>
#include <cstddef>

typedef unsigned int u32;
typedef unsigned short u16;
typedef __attribute__((ext_vector_type(8))) short bf16x8;   // 8 bf16 = 4 VGPR
typedef __attribute__((ext_vector_type(4))) float f32x4;

#define DEV __device__ __forceinline__

DEV u16 f2b(float f){ u32 x = __float_as_uint(f); x += 0x7fffu + ((x>>16)&1u); return (u16)(x>>16); }
DEV u32 pk2(float a, float b){
  u32 r;
  asm("v_cvt_pk_bf16_f32 %0, %1, %2" : "=v"(r) : "v"(a), "v"(b));
  return r;
}

DEV void gll16(const void* g, void* l){
  __builtin_amdgcn_global_load_lds((const __attribute__((address_space(1))) u32*)g,
                                   (__attribute__((address_space(3))) u32*)l, 16, 0, 0);
}

// token row -> (window, in-window index);  H=W=D=32, g=8
DEV void win_n(int r, int& win, int& n){
  int d_ = r & 31, w_ = (r>>5)&31, h_ = r>>10;
  win = ((h_>>3)<<4) | ((w_>>3)<<2) | (d_>>3);
  n   = ((h_&7)<<6)  | ((w_&7)<<3)  | (d_&7);
}
// window-order row -> token row
DEV int tok_of(int r){
  int win = r>>9, nn = r&511;
  int bh = win>>4, bw=(win>>2)&3, bd=win&3;
  int ih = nn>>6,  iw=(nn>>3)&7,  id=nn&7;
  return ((bh*8+ih)<<10) | ((bw*8+iw)<<5) | (bd*8+id);
}

// ---------------- small prep kernels ----------------

// all four weight transposes in one dispatch: dst bf16 [N][K] = transpose(src fp32 [K][N])
__global__ void wtrall_k(const float* __restrict__ qkv_w, const float* __restrict__ proj_w,
                         const float* __restrict__ fc1_w, const float* __restrict__ fc2_w,
                         u16* __restrict__ qkvT, u16* __restrict__ projT,
                         u16* __restrict__ fc1T, u16* __restrict__ fc2T){
  int f = blockIdx.x*256 + threadIdx.x;   // 786432 total
  const float* w; u16* wt; int g; bool k10 = false; int N;
  if (f < 196608)      { w=qkv_w;  wt=qkvT;  g=f;        N=768;  }
  else if (f < 262144) { w=proj_w; wt=projT; g=f-196608; N=256;  }
  else if (f < 524288) { w=fc1_w;  wt=fc1T;  g=f-262144; N=1024; }
  else                 { w=fc2_w;  wt=fc2T;  g=f-524288; N=256;  k10=true; }
  int n = k10 ? (g>>10) : (g>>8);
  int k = k10 ? (g&1023) : (g&255);
  wt[g] = f2b(w[(size_t)k*N + n]);
}

// position-bias MLP: one thread per table row (3375 rows); emits f32 per-head tables
// scaled by log2(e) so attention softmax can run in exp2 domain.
template<int NOUT>
DEV void pstage(float* v, const float* g, const float* b, const float* W, const float* bb){
  float m = 0.f;
  #pragma unroll
  for (int i=0;i<16;i++) m += v[i];
  m *= 0.0625f;
  float q = 0.f;
  #pragma unroll
  for (int i=0;i<16;i++){ float d=v[i]-m; q += d*d; }
  float rs = rsqrtf(q*0.0625f + 1e-5f);
  float u[16];
  #pragma unroll
  for (int i=0;i<16;i++){ float t = (v[i]-m)*rs*g[i] + b[i]; u[i] = t>0.f?t:0.f; }
  #pragma unroll
  for (int o=0;o<NOUT;o++){
    float s = bb[o];
    #pragma unroll
    for (int kk=0;kk<16;kk++) s += u[kk]*W[kk*NOUT+o];
    v[o] = s;
  }
}

__global__ void posmlp_k(const float* pp_w, const float* pp_b,
                         const float* g1, const float* b1, const float* w1, const float* bb1,
                         const float* g2, const float* b2, const float* w2, const float* bb2,
                         const float* g3, const float* b3, const float* w3, const float* bb3,
                         float* __restrict__ posb){
  int i = blockIdx.x*256 + threadIdx.x;
  if (i >= 3375) return;
  int t = i;
  int bd = t % 15; t /= 15;
  int bw = t % 15; t /= 15;
  int bh = t;
  float fh = (float)(bh-7), fw = (float)(bw-7), fd = (float)(bd-7);
  float v[16];
  #pragma unroll
  for (int o=0;o<16;o++) v[o] = fh*pp_w[o] + fw*pp_w[16+o] + fd*pp_w[32+o] + pp_b[o];
  pstage<16>(v, g1,b1,w1,bb1);
  pstage<16>(v, g2,b2,w2,bb2);
  pstage<8> (v, g3,b3,w3,bb3);
  #pragma unroll
  for (int h=0;h<8;h++) posb[(size_t)h*3376 + i] = v[h] * 1.4426950408889634f;
}

// ---------------- GEMM params ----------------
struct GemmP {
  const u16* A;          // bf16 A (STG==3 gather source)
  const float* Af32;     // fp32 A (STG 1/2)
  const float* lng; const float* lnb;   // LN gamma/beta (STG==1)
  const u16* Bt;
  int K;
  const float* bvec;
  float scale;
  const float* add32;
  float* out32;
  u16* out16;
  u16* out16b;
};

// shared epilogue: D layout col=lane&15, row=(lane>>4)*4+v  [verified m89]
template<int MODE>
DEV void epi(const GemmP& p, int r, int c, float val){
  if constexpr (MODE==0){           // Q: (val+b)*scale -> Q[win*8+h][n][d]
    float qv = (val + p.bvec[c]) * p.scale;
    int win, n; win_n(r, win, n);
    int hh = c>>5, dd = c&31;
    p.out16[((size_t)((win*8+hh)*512 + n)<<5) + dd] = f2b(qv);
  } else if constexpr (MODE==1){    // K (c<256) / V (c>=256), MFMA fragment layout
    float ov = val + p.bvec[c];
    int win, n; win_n(r, win, n);
    int cc = c & 255;
    int hh = cc>>5, dd = cc&31;
    size_t base = (size_t)(win*8+hh)*16384;
    if (c < 256){
      int nc = n>>4, ln2 = ((dd>>3)<<4)|(n&15), jj = dd&7;
      p.out16[base + (size_t)(nc*64+ln2)*8 + jj] = f2b(ov);
    } else {
      int fi = ((n>>5)<<1) | (dd>>4);
      int ln2 = (((n>>3)&3)<<4)|(dd&15), jj = n&7;
      p.out16b[base + (size_t)(fi*64+ln2)*8 + jj] = f2b(ov);
    }
  } else if constexpr (MODE==2){    // proj + x residual, window row -> token row
    int l = tok_of(r);
    size_t o = (size_t)l*256 + c;
    p.out32[o] = val + p.bvec[c] + p.add32[o];
  } else if constexpr (MODE==3){    // fc1 + fast tanh-GELU (<=1e-3 abs err vs exact erf)
    float u = val + p.bvec[c];
    float e = exp2f(u*(2.3022083f + 0.1029437f*u*u));
    float ge = u*e*__builtin_amdgcn_rcpf(e+1.f);
    p.out16[(size_t)r*1024 + c] = f2b(ge);
  } else {                          // fc2 + residual -> fp32 out
    size_t o = (size_t)r*256 + c;
    p.out32[o] = val + p.bvec[c] + p.add32[o];
  }
}

// ---------------- A-in-registers GEMM (K=256) ----------------------------------
// 64-row m-tile. A panel staged through LDS once then held in areg[2][8]; per k-step
// only B streams from LDS (3-buffer ring staged 2 ahead, counted vmcnt). LDS 32KB.
// STG: 1 = A fp32 + fused LayerNorm; 2 = A fp32 convert; 3 = A bf16 gather (attnF).
template<int MODE, int STG, int NT>
__global__ __launch_bounds__(512, 2)
void gemmA_k(GemmP p){
  __shared__ u16 smem[16384];   // 32KB: A-stage in prologue, then B-ring 3x8KB
  const int tid = threadIdx.x;
  const int wid = tid>>6, lane = tid&63;
  const int lr = lane&15, lg = lane>>4;
  const int m0 = blockIdx.x*64;
  const int wm = (wid>>2)*32, wn = (wid&3)*32;
  const int T = NT*8;
  const f32x4 z4 = {0.f,0.f,0.f,0.f};

  // --- prologue: A panel -> frag layout in smem
  if constexpr (STG==3){
    #pragma unroll
    for (int it=0; it<4; ++it){
      int f = it*8 + wid;
      int rt = f>>3, kt = f&7;
      int row = m0 + rt*16 + lr;
      gll16(p.A + ((size_t)((row>>9)*8 + kt)*512 + (row&511))*32 + lg*8,
            (char*)smem + f*1024 + lane*16);
    }
    asm volatile("s_waitcnt vmcnt(0)" ::: "memory");
    __builtin_amdgcn_s_barrier();
  } else {
    const int row = wid*8 + (lane>>3);     // 0..63 within tile
    const int sub = lane&7;
    const float* src = p.Af32 + (size_t)(m0+row)*256;
    float xv[32];
    #pragma unroll
    for (int j=0;j<8;j++){
      float4 v = *(const float4*)(src + j*32 + sub*4);
      xv[j*4+0]=v.x; xv[j*4+1]=v.y; xv[j*4+2]=v.z; xv[j*4+3]=v.w;
    }
    float mu=0.f, rs=1.f;
    if constexpr (STG==1){
      float s=0.f;
      #pragma unroll
      for (int i2=0;i2<32;i2++) s += xv[i2];
      s += __shfl_xor(s,1); s += __shfl_xor(s,2); s += __shfl_xor(s,4);
      mu = s*(1.f/256.f);
      float q2=0.f;
      #pragma unroll
      for (int i2=0;i2<32;i2++){ float d=xv[i2]-mu; q2 += d*d; }
      q2 += __shfl_xor(q2,1); q2 += __shfl_xor(q2,2); q2 += __shfl_xor(q2,4);
      rs = rsqrtf(q2*(1.f/256.f) + 1e-5f);
    }
    const int rt = wid>>1, q = (wid&1)*8 + (lane>>3);
    #pragma unroll
    for (int j=0;j<8;j++){
      float o0,o1,o2,o3;
      if constexpr (STG==1){
        float4 gg = *(const float4*)(p.lng + j*32 + sub*4);
        float4 bb = *(const float4*)(p.lnb + j*32 + sub*4);
        o0=(xv[j*4+0]-mu)*rs*gg.x+bb.x; o1=(xv[j*4+1]-mu)*rs*gg.y+bb.y;
        o2=(xv[j*4+2]-mu)*rs*gg.z+bb.z; o3=(xv[j*4+3]-mu)*rs*gg.w+bb.w;
      } else {
        o0=xv[j*4+0]; o1=xv[j*4+1]; o2=xv[j*4+2]; o3=xv[j*4+3];
      }
      int f = rt*8 + j;
      *(uint2*)((char*)smem + f*1024 + (sub>>1)*256 + q*16 + (sub&1)*8)
          = make_uint2((u32)f2b(o0) | ((u32)f2b(o1)<<16),
                       (u32)f2b(o2) | ((u32)f2b(o3)<<16));
    }
    asm volatile("s_waitcnt lgkmcnt(0)" ::: "memory");
    __builtin_amdgcn_s_barrier();
  }
  // A frags -> registers (compile-time indexed: rule-20 safe)
  bf16x8 areg[2][8];
  #pragma unroll
  for (int i=0;i<2;i++)
    #pragma unroll
    for (int kt=0;kt<8;kt++){
      int f = ((wid>>2)*2 + i)*8 + kt;
      areg[i][kt] = *(const bf16x8*)((const char*)smem + f*1024 + lane*16);
    }
  asm volatile("s_waitcnt lgkmcnt(0)" ::: "memory");
  __builtin_amdgcn_s_barrier();     // all reads done before ring overwrites

  u16* lB = smem;                   // 3 bufs x 8KB, aliases the dead A-stage
  auto stageB = [&](int buf, int t){
    int j = t>>3, kt = t&7;
    gll16(p.Bt + (size_t)(j*128 + wid*16 + lr)*256 + kt*32 + lg*8,
          (char*)lB + buf*8192 + wid*1024 + lane*16);
  };
  stageB(0, 0);
  if (T > 1) stageB(1, 1);

  constexpr int EPIW = (MODE==2) ? 33 : 17;   // epilogue ops + 1 stage in flight
  f32x4 acc[2][2];
  #pragma unroll
  for (int i=0;i<2;i++){ acc[i][0]=z4; acc[i][1]=z4; }

  int cur = 0, stg = 2, t = 0;
  for (int j=0; j<NT; ++j){
    #pragma unroll
    for (int kt=0; kt<8; ++kt, ++t){
      if (t+1 >= T)        asm volatile("s_waitcnt vmcnt(0)" ::: "memory");
      else if (kt==0 && t) asm volatile("s_waitcnt vmcnt(%0)" :: "i"(EPIW) : "memory");
      else                 asm volatile("s_waitcnt vmcnt(1)" ::: "memory");
      __builtin_amdgcn_s_barrier();
      __builtin_amdgcn_sched_barrier(0);
      bf16x8 bfr[2];
      #pragma unroll
      for (int jj=0;jj<2;jj++)
        bfr[jj] = *(const bf16x8*)((const char*)lB + cur*8192 + ((wid&3)*2+jj)*1024 + lane*16);
      #pragma unroll
      for (int i=0;i<2;i++)
        #pragma unroll
        for (int jj=0;jj<2;jj++)
          acc[i][jj] = __builtin_amdgcn_mfma_f32_16x16x32_bf16(areg[i][kt], bfr[jj], acc[i][jj], 0,0,0);
      __builtin_amdgcn_sched_barrier(0);
      if (kt == 7){
        int n0 = j*128;
        #pragma unroll
        for (int i=0;i<2;i++)
          #pragma unroll
          for (int jj=0;jj<2;jj++){
            #pragma unroll
            for (int v=0;v<4;v++)
              epi<MODE>(p, m0 + wm + i*16 + lg*4 + v, n0 + wn + jj*16 + lr, acc[i][jj][v]);
            acc[i][jj] = z4;
          }
      }
      if (t+2 < T) stageB(stg, t+2);
      cur = (cur==2)?0:cur+1;
      stg = (stg==2)?0:stg+1;
    }
  }
}

// ---------------- fc2 GEMM (K=1024, N=256): 512 threads, n-resident ----------------
__global__ __launch_bounds__(512, 2)
void gemmW_k(GemmP p){
  __shared__ u16 lA[3][2048];   // 4 frags/buf
  __shared__ u16 lB[3][8192];   // 16 frags/buf
  const int tid = threadIdx.x;
  const int wid = tid>>6, lane = tid&63;
  const int lr = lane&15, lg = lane>>4;
  const int m0 = blockIdx.x*64;
  const int wm = (wid>>2)*32, wn = (wid&3)*64;
  const f32x4 z4 = {0.f,0.f,0.f,0.f};

  auto stage = [&](int buf, int kt){
    // A: half-fragment per wave (lanes 0-31 active)
    {
      int f = wid>>1, half = wid&1;
      if (lane < 32){
        int lg2 = half*2 + (lane>>4);
        gll16(p.A + (size_t)(m0 + f*16 + (lane&15))*1024 + kt*32 + lg2*8,
              (char*)lA[buf] + f*1024 + half*512 + lane*16);
      }
    }
    #pragma unroll
    for (int r=0;r<2;r++){
      int fb = wid*2 + r;
      gll16(p.Bt + (size_t)(fb*16 + lr)*1024 + kt*32 + lg*8,
            (char*)lB[buf] + fb*1024 + lane*16);
    }
  };
  stage(0, 0);
  stage(1, 1);

  f32x4 acc[2][4];
  #pragma unroll
  for (int i=0;i<2;i++)
    #pragma unroll
    for (int j=0;j<4;j++) acc[i][j] = z4;

  int cur = 0, stg = 2;
  for (int kt=0; kt<32; ++kt){
    if (kt+1 < 32) asm volatile("s_waitcnt vmcnt(3)" ::: "memory");
    else           asm volatile("s_waitcnt vmcnt(0)" ::: "memory");
    __builtin_amdgcn_s_barrier();
    __builtin_amdgcn_sched_barrier(0);
    bf16x8 af[2], bfr[4];
    #pragma unroll
    for (int i=0;i<2;i++){
      int fA = (wid>>2)*2 + i;
      af[i] = *(const bf16x8*)((const char*)lA[cur] + fA*1024 + lane*16);
    }
    #pragma unroll
    for (int j=0;j<4;j++){
      int fB = (wid&3)*4 + j;
      bfr[j] = *(const bf16x8*)((const char*)lB[cur] + fB*1024 + lane*16);
    }
    #pragma unroll
    for (int i=0;i<2;i++)
      #pragma unroll
      for (int j=0;j<4;j++)
        acc[i][j] = __builtin_amdgcn_mfma_f32_16x16x32_bf16(af[i], bfr[j], acc[i][j], 0,0,0);
    __builtin_amdgcn_sched_barrier(0);
    if (kt+2 < 32) stage(stg, kt+2);
    cur = (cur==2)?0:cur+1;
    stg = (stg==2)?0:stg+1;
  }

  #pragma unroll
  for (int i=0;i<2;i++)
    #pragma unroll
    for (int j=0;j<4;j++)
      #pragma unroll
      for (int v=0;v<4;v++)
        epi<4>(p, m0 + wm + i*16 + lg*4 + v, wn + j*16 + lr, acc[i][j][v]);
}

// ---------------- attention: one block per (window, head), 8 waves, 2-phase ----------------
// exp2-domain softmax, fixed reference (no max pass — scores bounded for this problem).
// Row-sum via ones-MFMA: normalizer lands in the lane's own row slot, no shuffles.
__global__ __launch_bounds__(512, 2)
void attn_k(const u16* __restrict__ Q, const u16* __restrict__ Kf,
            const u16* __restrict__ Vf, const float* __restrict__ posb,
            u16* __restrict__ outF){
  __shared__ u16 lK[16384];      // 32 frags x 1KB, fragment order
  __shared__ u16 lV[16384];      // 32 frags x 1KB (16 kc x 2 dblk)
  __shared__ float lPf[3392];    // pos table f32 (x log2e)
  const int bid = blockIdx.x;
  const int hh = bid&7;
  const int tid = threadIdx.x, wid = tid>>6, lane = tid&63;
  const int lr = lane&15, lg = lane>>4;
  const u16* Kb = Kf + (size_t)bid*16384;
  const u16* Vb = Vf + (size_t)bid*16384;
  const u16* Qb = Q  + (size_t)bid*16384;
  #pragma unroll
  for (int r=0;r<4;r++){
    int off = (r*512 + tid)*16;
    gll16((const char*)Kb + off, (char*)lK + off);
    gll16((const char*)Vb + off, (char*)lV + off);
  }
  const float* ptab = posb + (size_t)hh*3376;
  for (int t=tid; t<3375; t+=512) lPf[t] = ptab[t];
  __syncthreads();
  const f32x4 z4 = {0.f,0.f,0.f,0.f};
  const bf16x8 ones = {(short)0x3F80,(short)0x3F80,(short)0x3F80,(short)0x3F80,
                       (short)0x3F80,(short)0x3F80,(short)0x3F80,(short)0x3F80};

  for (int ch=0; ch<4; ++ch){
    const int r0 = wid*64 + ch*16;
    const int q  = r0 + lr;
    // bias index base: idx(nc,v) = Ab - (nc>>2)*225 - (nc&3)*30 - v
    const int Ab = (q>>6)*225 + ((q>>3)&7)*15 + (q&7) + 1687 - (lg>>1)*15 - (lg&1)*4;
    bf16x8 qf = *(const bf16x8*)(Qb + (size_t)q*32 + lg*8);
    f32x4 o0 = z4, o1 = z4, as_ = z4;
    #pragma unroll
    for (int ph=0; ph<2; ++ph){
      // S^T frags for this half: sf[i][v] = S[q][n=(ph*16+i)*16+lg*4+v]  (exp2 domain)
      f32x4 sf[16];
      __builtin_amdgcn_s_setprio(1);
      #pragma unroll
      for (int i=0;i<16;i++){
        int nc = ph*16 + i;
        bf16x8 kf = *(const bf16x8*)&lK[(nc*64 + lane)*8];
        sf[i] = __builtin_amdgcn_mfma_f32_16x16x32_bf16(kf, qf, z4, 0,0,0);
      }
      __builtin_amdgcn_s_setprio(0);
      // P = exp2(S + bias)
      #pragma unroll
      for (int i=0;i<16;i++){
        int nc = ph*16 + i;
        const float* bp = lPf + (Ab - (nc>>2)*225 - (nc&3)*30 - 3);
        sf[i][3] = exp2f(sf[i][3] + bp[0]);
        sf[i][2] = exp2f(sf[i][2] + bp[1]);
        sf[i][1] = exp2f(sf[i][1] + bp[2]);
        sf[i][0] = exp2f(sf[i][0] + bp[3]);
      }
      // PV + ones-MFMA rowsum over this half's 8 kc blocks
      #pragma unroll
      for (int kc=0;kc<8;kc++){
        u32 a0 = pk2(sf[2*kc  ][0], sf[2*kc  ][1]);
        u32 a1 = pk2(sf[2*kc  ][2], sf[2*kc  ][3]);
        u32 b0 = pk2(sf[2*kc+1][0], sf[2*kc+1][1]);
        u32 b1 = pk2(sf[2*kc+1][2], sf[2*kc+1][3]);
        asm("v_permlane32_swap_b32 %0, %1" : "+v"(a0), "+v"(b0));
        asm("v_permlane16_swap_b32 %0, %1" : "+v"(a0), "+v"(b0));  // a0=T0, b0=T2
        asm("v_permlane32_swap_b32 %0, %1" : "+v"(a1), "+v"(b1));
        asm("v_permlane16_swap_b32 %0, %1" : "+v"(a1), "+v"(b1));  // a1=T1, b1=T3
        bf16x8 pf;
        ((u32*)&pf)[0]=a0; ((u32*)&pf)[1]=a1; ((u32*)&pf)[2]=b0; ((u32*)&pf)[3]=b1;
        int kcg = ph*8 + kc;
        bf16x8 v0 = *(const bf16x8*)&lV[(size_t)((kcg*2+0)*64 + lane)*8];
        bf16x8 v1 = *(const bf16x8*)&lV[(size_t)((kcg*2+1)*64 + lane)*8];
        __builtin_amdgcn_s_setprio(1);
        o0  = __builtin_amdgcn_mfma_f32_16x16x32_bf16(pf, v0, o0, 0,0,0);
        o1  = __builtin_amdgcn_mfma_f32_16x16x32_bf16(pf, v1, o1, 0,0,0);
        as_ = __builtin_amdgcn_mfma_f32_16x16x32_bf16(pf, ones, as_, 0,0,0);
        __builtin_amdgcn_s_setprio(0);
      }
    }
    #pragma unroll
    for (int v=0;v<4;v++){
      float inv = 1.0f / as_[v];          // rowsum already in this lane's row slot
      int n = r0 + lg*4 + v;
      size_t base = ((size_t)bid*512 + n)*32;
      outF[base + lr]      = f2b(o0[v]*inv);
      outF[base + 16 + lr] = f2b(o1[v]*inv);
    }
  }
}

// ---------------- host launch ----------------
extern "C" void kernel_launch(void* const* d_in, const int* in_sizes, int n_in,
                              void* d_out, int out_size, void* d_ws, size_t ws_size,
                              hipStream_t stream){
  const float* x      = (const float*)d_in[0];
  const float* y      = (const float*)d_in[1];
  const float* n1_g   = (const float*)d_in[2];
  const float* n1_b   = (const float*)d_in[3];
  const float* qkv_w  = (const float*)d_in[4];
  const float* qkv_b  = (const float*)d_in[5];
  const float* pp_w   = (const float*)d_in[6];
  const float* pp_b   = (const float*)d_in[7];
  const float* p1_lng = (const float*)d_in[8];
  const float* p1_lnb = (const float*)d_in[9];
  const float* p1_w   = (const float*)d_in[10];
  const float* p1_b   = (const float*)d_in[11];
  const float* p2_lng = (const float*)d_in[12];
  const float* p2_lnb = (const float*)d_in[13];
  const float* p2_w   = (const float*)d_in[14];
  const float* p2_b   = (const float*)d_in[15];
  const float* p3_lng = (const float*)d_in[16];
  const float* p3_lnb = (const float*)d_in[17];
  const float* p3_w   = (const float*)d_in[18];
  const float* p3_b   = (const float*)d_in[19];
  const float* proj_w = (const float*)d_in[20];
  const float* proj_b = (const float*)d_in[21];
  const float* n2_g   = (const float*)d_in[22];
  const float* n2_b   = (const float*)d_in[23];
  const float* fc1_w  = (const float*)d_in[24];
  const float* fc1_b  = (const float*)d_in[25];
  const float* fc2_w  = (const float*)d_in[26];
  const float* fc2_b  = (const float*)d_in[27];
  float* out = (float*)d_out;
  char* ws = (char*)d_ws;

  // workspace layout (bytes)
  u16*   qkvT  = (u16*)  (ws + 0);          // [768][256] bf16
  u16*   projT = (u16*)  (ws + 393216);     // [256][256]
  u16*   fc1T  = (u16*)  (ws + 524288);     // [1024][256]
  u16*   fc2T  = (u16*)  (ws + 1048576);    // [256][1024]
  float* posb  = (float*)(ws + 1572864);    // [8][3376] f32 per-head pos tables (x log2e)
  u16*   hbuf  = (u16*)  (ws + 5898240);    // MLP hidden [32768][1024] bf16 (67 MB)
  u16*   Qb    = (u16*)  (ws + 39452672);   // [512 bh][512 n][32 d]   (dead by fc1)
  u16*   Kfb   = (u16*)  (ws + 56229888);   // [512 bh][32 frag][64 lane][8]  (dead by fc1)
  u16*   Vfb   = (u16*)  (ws + 73007104);   // [512 bh][32 frag][64 lane][8]  (dead by proj)
  u16*   attnF = (u16*)  (ws + 89784320);   // [512 bh][512 n][32 d] block-contiguous
  float* xres  = (float*)(ws + 106561536);  // [32768][256] fp32   (end 140,115,968)

  wtrall_k<<<3072,256,0,stream>>>(qkv_w, proj_w, fc1_w, fc2_w, qkvT, projT, fc1T, fc2T);
  posmlp_k<<<14,256,0,stream>>>(pp_w, pp_b,
                                p1_lng,p1_lnb,p1_w,p1_b,
                                p2_lng,p2_lnb,p2_w,p2_b,
                                p3_lng,p3_lnb,p3_w,p3_b, posb);

  GemmP pq; pq.A=nullptr; pq.Af32=x; pq.lng=n1_g; pq.lnb=n1_b;
  pq.Bt=qkvT; pq.K=256; pq.bvec=qkv_b;
  pq.scale=0.17677669529663687f*1.4426950408889634f;  // hd^-0.5 * log2(e)
  pq.add32=nullptr; pq.out32=nullptr; pq.out16=Qb; pq.out16b=nullptr;
  gemmA_k<0,1,2><<<512,512,0,stream>>>(pq);

  GemmP pkv; pkv.A=nullptr; pkv.Af32=y; pkv.lng=nullptr; pkv.lnb=nullptr;
  pkv.Bt=qkvT + 256*256; pkv.K=256; pkv.bvec=qkv_b + 256;
  pkv.scale=1.f; pkv.add32=nullptr; pkv.out32=nullptr; pkv.out16=Kfb; pkv.out16b=Vfb;
  gemmA_k<1,2,4><<<512,512,0,stream>>>(pkv);

  attn_k<<<512,512,0,stream>>>(Qb, Kfb, Vfb, posb, attnF);

  GemmP pp; pp.A=attnF; pp.Af32=nullptr; pp.lng=nullptr; pp.lnb=nullptr;
  pp.Bt=projT; pp.K=256; pp.bvec=proj_b;
  pp.scale=1.f; pp.add32=x; pp.out32=xres; pp.out16=nullptr; pp.out16b=nullptr;
  gemmA_k<2,3,2><<<512,512,0,stream>>>(pp);

  GemmP pf1; pf1.A=nullptr; pf1.Af32=xres; pf1.lng=n2_g; pf1.lnb=n2_b;
  pf1.Bt=fc1T; pf1.K=256; pf1.bvec=fc1_b;
  pf1.scale=1.f; pf1.add32=nullptr; pf1.out32=nullptr; pf1.out16=hbuf; pf1.out16b=nullptr;
  gemmA_k<3,1,8><<<512,512,0,stream>>>(pf1);

  GemmP pf2; pf2.A=hbuf; pf2.Af32=nullptr; pf2.lng=nullptr; pf2.lnb=nullptr;
  pf2.Bt=fc2T; pf2.K=1024; pf2.bvec=fc2_b;
  pf2.scale=1.f; pf2.add32=xres; pf2.out32=out; pf2.out16=nullptr; pf2.out16b=nullptr;
  gemmW_k<<<512,512,0,stream>>>(pf2);
}

// Round 16
// 244.991 us; speedup vs baseline: 1.0293x; 1.0064x over previous
//
#include <hip/hip_runtime.h>
#include <cstdint>
#include <cstddef>

typedef unsigned int u32;
typedef unsigned short u16;
typedef __attribute__((ext_vector_type(8))) short bf16x8;   // 8 bf16 = 4 VGPR
typedef __attribute__((ext_vector_type(4))) float f32x4;

#define DEV __device__ __forceinline__

DEV u16 f2b(float f){ u32 x = __float_as_uint(f); x += 0x7fffu + ((x>>16)&1u); return (u16)(x>>16); }
DEV u32 pk2(float a, float b){
  u32 r;
  asm("v_cvt_pk_bf16_f32 %0, %1, %2" : "=v"(r) : "v"(a), "v"(b));
  return r;
}

DEV void gll16(const void* g, void* l){
  __builtin_amdgcn_global_load_lds((const __attribute__((address_space(1))) u32*)g,
                                   (__attribute__((address_space(3))) u32*)l, 16, 0, 0);
}

// token row -> (window, in-window index);  H=W=D=32, g=8
DEV void win_n(int r, int& win, int& n){
  int d_ = r & 31, w_ = (r>>5)&31, h_ = r>>10;
  win = ((h_>>3)<<4) | ((w_>>3)<<2) | (d_>>3);
  n   = ((h_&7)<<6)  | ((w_&7)<<3)  | (d_&7);
}
// window-order row -> token row
DEV int tok_of(int r){
  int win = r>>9, nn = r&511;
  int bh = win>>4, bw=(win>>2)&3, bd=win&3;
  int ih = nn>>6,  iw=(nn>>3)&7,  id=nn&7;
  return ((bh*8+ih)<<10) | ((bw*8+iw)<<5) | (bd*8+id);
}

// ---------------- small prep kernels ----------------

// all four weight transposes in one dispatch: dst bf16 [N][K] = transpose(src fp32 [K][N])
__global__ void wtrall_k(const float* __restrict__ qkv_w, const float* __restrict__ proj_w,
                         const float* __restrict__ fc1_w, const float* __restrict__ fc2_w,
                         u16* __restrict__ qkvT, u16* __restrict__ projT,
                         u16* __restrict__ fc1T, u16* __restrict__ fc2T){
  int f = blockIdx.x*256 + threadIdx.x;   // 786432 total
  const float* w; u16* wt; int g; bool k10 = false; int N;
  if (f < 196608)      { w=qkv_w;  wt=qkvT;  g=f;        N=768;  }
  else if (f < 262144) { w=proj_w; wt=projT; g=f-196608; N=256;  }
  else if (f < 524288) { w=fc1_w;  wt=fc1T;  g=f-262144; N=1024; }
  else                 { w=fc2_w;  wt=fc2T;  g=f-524288; N=256;  k10=true; }
  int n = k10 ? (g>>10) : (g>>8);
  int k = k10 ? (g&1023) : (g&255);
  wt[g] = f2b(w[(size_t)k*N + n]);
}

// position-bias MLP: one thread per table row (3375 rows); emits f32 per-head tables
// scaled by log2(e) so attention softmax can run in exp2 domain.
template<int NOUT>
DEV void pstage(float* v, const float* g, const float* b, const float* W, const float* bb){
  float m = 0.f;
  #pragma unroll
  for (int i=0;i<16;i++) m += v[i];
  m *= 0.0625f;
  float q = 0.f;
  #pragma unroll
  for (int i=0;i<16;i++){ float d=v[i]-m; q += d*d; }
  float rs = rsqrtf(q*0.0625f + 1e-5f);
  float u[16];
  #pragma unroll
  for (int i=0;i<16;i++){ float t = (v[i]-m)*rs*g[i] + b[i]; u[i] = t>0.f?t:0.f; }
  #pragma unroll
  for (int o=0;o<NOUT;o++){
    float s = bb[o];
    #pragma unroll
    for (int kk=0;kk<16;kk++) s += u[kk]*W[kk*NOUT+o];
    v[o] = s;
  }
}

__global__ void posmlp_k(const float* pp_w, const float* pp_b,
                         const float* g1, const float* b1, const float* w1, const float* bb1,
                         const float* g2, const float* b2, const float* w2, const float* bb2,
                         const float* g3, const float* b3, const float* w3, const float* bb3,
                         float* __restrict__ posb){
  int i = blockIdx.x*256 + threadIdx.x;
  if (i >= 3375) return;
  int t = i;
  int bd = t % 15; t /= 15;
  int bw = t % 15; t /= 15;
  int bh = t;
  float fh = (float)(bh-7), fw = (float)(bw-7), fd = (float)(bd-7);
  float v[16];
  #pragma unroll
  for (int o=0;o<16;o++) v[o] = fh*pp_w[o] + fw*pp_w[16+o] + fd*pp_w[32+o] + pp_b[o];
  pstage<16>(v, g1,b1,w1,bb1);
  pstage<16>(v, g2,b2,w2,bb2);
  pstage<8> (v, g3,b3,w3,bb3);
  #pragma unroll
  for (int h=0;h<8;h++) posb[(size_t)h*3376 + i] = v[h] * 1.4426950408889634f;
}

// ---------------- GEMM params ----------------
struct GemmP {
  const u16* A;          // bf16 A (STG==3 gather source)
  const float* Af32;     // fp32 A (STG 1/2)
  const float* lng; const float* lnb;   // LN gamma/beta (STG==1)
  const u16* Bt;
  int K;
  const float* bvec;
  float scale;
  const float* add32;
  float* out32;
  u16* out16;
  u16* out16b;
};

// shared epilogue: D layout col=lane&15, row=(lane>>4)*4+v  [verified m89]
template<int MODE>
DEV void epi(const GemmP& p, int r, int c, float val){
  if constexpr (MODE==0){           // Q: (val+b)*scale -> Q[win*8+h][n][d]
    float qv = (val + p.bvec[c]) * p.scale;
    int win, n; win_n(r, win, n);
    int hh = c>>5, dd = c&31;
    p.out16[((size_t)((win*8+hh)*512 + n)<<5) + dd] = f2b(qv);
  } else if constexpr (MODE==1){    // K (c<256) / V (c>=256), MFMA fragment layout
    float ov = val + p.bvec[c];
    int win, n; win_n(r, win, n);
    int cc = c & 255;
    int hh = cc>>5, dd = cc&31;
    size_t base = (size_t)(win*8+hh)*16384;
    if (c < 256){
      int nc = n>>4, ln2 = ((dd>>3)<<4)|(n&15), jj = dd&7;
      p.out16[base + (size_t)(nc*64+ln2)*8 + jj] = f2b(ov);
    } else {
      int fi = ((n>>5)<<1) | (dd>>4);
      int ln2 = (((n>>3)&3)<<4)|(dd&15), jj = n&7;
      p.out16b[base + (size_t)(fi*64+ln2)*8 + jj] = f2b(ov);
    }
  } else if constexpr (MODE==2){    // proj + x residual, window row -> token row
    int l = tok_of(r);
    size_t o = (size_t)l*256 + c;
    p.out32[o] = val + p.bvec[c] + p.add32[o];
  } else if constexpr (MODE==3){    // fc1 + fast tanh-GELU (<=1e-3 abs err vs exact erf)
    float u = val + p.bvec[c];
    float e = exp2f(u*(2.3022083f + 0.1029437f*u*u));
    float ge = u*e*__builtin_amdgcn_rcpf(e+1.f);
    p.out16[(size_t)r*1024 + c] = f2b(ge);
  } else {                          // fc2 + residual -> fp32 out
    size_t o = (size_t)r*256 + c;
    p.out32[o] = val + p.bvec[c] + p.add32[o];
  }
}

// ---------------- A-in-registers GEMM (K=256), deep B-pipeline ------------------
// 64-row m-tile. A panel staged through LDS once then held in areg[2][8]; per k-step
// only B streams from LDS. B-ring: 6 buffers (48KB), prefetch 4 k-steps ahead,
// steady wait vmcnt(3). Tail waits count remaining newer stages exactly:
// t=T-3 -> vmcnt(2), t=T-2 -> vmcnt(1), t=T-1 -> vmcnt(0)   [r14 bug: these were 3]
// Post-epilogue iteration waits (19/35) are proven OVER-waits (newer = 3 stages +
// 18/34 epilogue ops) -> safe; asm "memory" clobbers pin epilogue ops between fences.
// STG: 1 = A fp32 + fused LayerNorm; 2 = A fp32 convert; 3 = A bf16 gather (attnF).
template<int MODE, int STG, int NT>
__global__ __launch_bounds__(512, 2)
void gemmA_k(GemmP p){
  __shared__ u16 smem[24576];   // 48KB: A-stage (32KB) in prologue, then B-ring 6x8KB
  const int tid = threadIdx.x;
  const int wid = tid>>6, lane = tid&63;
  const int lr = lane&15, lg = lane>>4;
  const int m0 = blockIdx.x*64;
  const int wm = (wid>>2)*32, wn = (wid&3)*32;
  const int T = NT*8;
  const f32x4 z4 = {0.f,0.f,0.f,0.f};

  // --- prologue: A panel -> frag layout in smem
  if constexpr (STG==3){
    #pragma unroll
    for (int it=0; it<4; ++it){
      int f = it*8 + wid;
      int rt = f>>3, kt = f&7;
      int row = m0 + rt*16 + lr;
      gll16(p.A + ((size_t)((row>>9)*8 + kt)*512 + (row&511))*32 + lg*8,
            (char*)smem + f*1024 + lane*16);
    }
    asm volatile("s_waitcnt vmcnt(0)" ::: "memory");
    __builtin_amdgcn_s_barrier();
  } else {
    const int row = wid*8 + (lane>>3);     // 0..63 within tile
    const int sub = lane&7;
    const float* src = p.Af32 + (size_t)(m0+row)*256;
    float xv[32];
    #pragma unroll
    for (int j=0;j<8;j++){
      float4 v = *(const float4*)(src + j*32 + sub*4);
      xv[j*4+0]=v.x; xv[j*4+1]=v.y; xv[j*4+2]=v.z; xv[j*4+3]=v.w;
    }
    float mu=0.f, rs=1.f;
    if constexpr (STG==1){
      float s=0.f;
      #pragma unroll
      for (int i2=0;i2<32;i2++) s += xv[i2];
      s += __shfl_xor(s,1); s += __shfl_xor(s,2); s += __shfl_xor(s,4);
      mu = s*(1.f/256.f);
      float q2=0.f;
      #pragma unroll
      for (int i2=0;i2<32;i2++){ float d=xv[i2]-mu; q2 += d*d; }
      q2 += __shfl_xor(q2,1); q2 += __shfl_xor(q2,2); q2 += __shfl_xor(q2,4);
      rs = rsqrtf(q2*(1.f/256.f) + 1e-5f);
    }
    const int rt = wid>>1, q = (wid&1)*8 + (lane>>3);
    #pragma unroll
    for (int j=0;j<8;j++){
      float o0,o1,o2,o3;
      if constexpr (STG==1){
        float4 gg = *(const float4*)(p.lng + j*32 + sub*4);
        float4 bb = *(const float4*)(p.lnb + j*32 + sub*4);
        o0=(xv[j*4+0]-mu)*rs*gg.x+bb.x; o1=(xv[j*4+1]-mu)*rs*gg.y+bb.y;
        o2=(xv[j*4+2]-mu)*rs*gg.z+bb.z; o3=(xv[j*4+3]-mu)*rs*gg.w+bb.w;
      } else {
        o0=xv[j*4+0]; o1=xv[j*4+1]; o2=xv[j*4+2]; o3=xv[j*4+3];
      }
      int f = rt*8 + j;
      *(uint2*)((char*)smem + f*1024 + (sub>>1)*256 + q*16 + (sub&1)*8)
          = make_uint2((u32)f2b(o0) | ((u32)f2b(o1)<<16),
                       (u32)f2b(o2) | ((u32)f2b(o3)<<16));
    }
    asm volatile("s_waitcnt lgkmcnt(0)" ::: "memory");
    __builtin_amdgcn_s_barrier();
  }
  // A frags -> registers (compile-time indexed: rule-20 safe)
  bf16x8 areg[2][8];
  #pragma unroll
  for (int i=0;i<2;i++)
    #pragma unroll
    for (int kt=0;kt<8;kt++){
      int f = ((wid>>2)*2 + i)*8 + kt;
      areg[i][kt] = *(const bf16x8*)((const char*)smem + f*1024 + lane*16);
    }
  asm volatile("s_waitcnt lgkmcnt(0)" ::: "memory");
  __builtin_amdgcn_s_barrier();     // all reads done before ring overwrites

  u16* lB = smem;                   // 6 bufs x 8KB, aliases the dead A-stage
  auto stageB = [&](int buf, int t){
    int j = t>>3, kt = t&7;
    gll16(p.Bt + (size_t)(j*128 + wid*16 + lr)*256 + kt*32 + lg*8,
          (char*)lB + buf*8192 + wid*1024 + lane*16);
  };
  stageB(0, 0); stageB(1, 1); stageB(2, 2); stageB(3, 3);   // T >= 16 always

  constexpr int EPIW = (MODE==2) ? 35 : 19;   // post-epilogue over-wait (safe)
  f32x4 acc[2][2];
  #pragma unroll
  for (int i=0;i<2;i++){ acc[i][0]=z4; acc[i][1]=z4; }

  int cur = 0, stg = 4, t = 0;
  for (int j=0; j<NT; ++j){
    #pragma unroll
    for (int kt=0; kt<8; ++kt, ++t){
      if (t+1 >= T)        asm volatile("s_waitcnt vmcnt(0)" ::: "memory");
      else if (t+2 >= T)   asm volatile("s_waitcnt vmcnt(1)" ::: "memory");
      else if (t+3 >= T)   asm volatile("s_waitcnt vmcnt(2)" ::: "memory");
      else if (kt==0 && t) asm volatile("s_waitcnt vmcnt(%0)" :: "i"(EPIW) : "memory");
      else                 asm volatile("s_waitcnt vmcnt(3)" ::: "memory");
      __builtin_amdgcn_s_barrier();
      __builtin_amdgcn_sched_barrier(0);
      bf16x8 bfr[2];
      #pragma unroll
      for (int jj=0;jj<2;jj++)
        bfr[jj] = *(const bf16x8*)((const char*)lB + cur*8192 + ((wid&3)*2+jj)*1024 + lane*16);
      #pragma unroll
      for (int i=0;i<2;i++)
        #pragma unroll
        for (int jj=0;jj<2;jj++)
          acc[i][jj] = __builtin_amdgcn_mfma_f32_16x16x32_bf16(areg[i][kt], bfr[jj], acc[i][jj], 0,0,0);
      __builtin_amdgcn_sched_barrier(0);
      if (kt == 7){
        int n0 = j*128;
        #pragma unroll
        for (int i=0;i<2;i++)
          #pragma unroll
          for (int jj=0;jj<2;jj++){
            #pragma unroll
            for (int v=0;v<4;v++)
              epi<MODE>(p, m0 + wm + i*16 + lg*4 + v, n0 + wn + jj*16 + lr, acc[i][jj][v]);
            acc[i][jj] = z4;
          }
      }
      if (t+4 < T) stageB(stg, t+4);
      cur = (cur==5)?0:cur+1;
      stg = (stg==5)?0:stg+1;
    }
  }
}

// ---------------- fc2 GEMM (K=1024, N=256): n-resident, 4-deep ring ----------------
// stage = 3 gll16/wave; prefetch 3 ahead; steady vmcnt(6); TAIL: kt=30 has only
// stages {30,31} = 6 ops outstanding, so vmcnt(6) would NOT wait (r14 bug) ->
// kt==30 uses vmcnt(3), kt==31 vmcnt(0).
__global__ __launch_bounds__(512, 2)
void gemmW_k(GemmP p){
  __shared__ u16 lA[4][2048];   // 4 frags/buf
  __shared__ u16 lB[4][8192];   // 16 frags/buf   (total 80KB -> 2 blocks/CU)
  const int tid = threadIdx.x;
  const int wid = tid>>6, lane = tid&63;
  const int lr = lane&15, lg = lane>>4;
  const int m0 = blockIdx.x*64;
  const int wm = (wid>>2)*32, wn = (wid&3)*64;
  const f32x4 z4 = {0.f,0.f,0.f,0.f};

  auto stage = [&](int buf, int kt){
    // A: half-fragment per wave (lanes 0-31 active)
    {
      int f = wid>>1, half = wid&1;
      if (lane < 32){
        int lg2 = half*2 + (lane>>4);
        gll16(p.A + (size_t)(m0 + f*16 + (lane&15))*1024 + kt*32 + lg2*8,
              (char*)lA[buf] + f*1024 + half*512 + lane*16);
      }
    }
    #pragma unroll
    for (int r=0;r<2;r++){
      int fb = wid*2 + r;
      gll16(p.Bt + (size_t)(fb*16 + lr)*1024 + kt*32 + lg*8,
            (char*)lB[buf] + fb*1024 + lane*16);
    }
  };
  stage(0, 0);
  stage(1, 1);
  stage(2, 2);

  f32x4 acc[2][4];
  #pragma unroll
  for (int i=0;i<2;i++)
    #pragma unroll
    for (int j=0;j<4;j++) acc[i][j] = z4;

  int cur = 0, stg = 3;
  for (int kt=0; kt<32; ++kt){
    if (kt+1 >= 32)      asm volatile("s_waitcnt vmcnt(0)" ::: "memory");
    else if (kt+2 >= 32) asm volatile("s_waitcnt vmcnt(3)" ::: "memory");
    else                 asm volatile("s_waitcnt vmcnt(6)" ::: "memory");
    __builtin_amdgcn_s_barrier();
    __builtin_amdgcn_sched_barrier(0);
    bf16x8 af[2], bfr[4];
    #pragma unroll
    for (int i=0;i<2;i++){
      int fA = (wid>>2)*2 + i;
      af[i] = *(const bf16x8*)((const char*)lA[cur] + fA*1024 + lane*16);
    }
    #pragma unroll
    for (int j=0;j<4;j++){
      int fB = (wid&3)*4 + j;
      bfr[j] = *(const bf16x8*)((const char*)lB[cur] + fB*1024 + lane*16);
    }
    #pragma unroll
    for (int i=0;i<2;i++)
      #pragma unroll
      for (int j=0;j<4;j++)
        acc[i][j] = __builtin_amdgcn_mfma_f32_16x16x32_bf16(af[i], bfr[j], acc[i][j], 0,0,0);
    __builtin_amdgcn_sched_barrier(0);
    if (kt+3 < 32) stage(stg, kt+3);
    cur = (cur+1)&3;
    stg = (stg+1)&3;
  }

  #pragma unroll
  for (int i=0;i<2;i++)
    #pragma unroll
    for (int j=0;j<4;j++)
      #pragma unroll
      for (int v=0;v<4;v++)
        epi<4>(p, m0 + wm + i*16 + lg*4 + v, wn + j*16 + lr, acc[i][j][v]);
}

// ---------------- attention: one block per (window, head), 8 waves, 2-phase ----------------
// exp2-domain softmax, fixed reference (no max pass — scores bounded for this problem).
// Row-sum via ones-MFMA: normalizer lands in the lane's own row slot, no shuffles.
__global__ __launch_bounds__(512, 2)
void attn_k(const u16* __restrict__ Q, const u16* __restrict__ Kf,
            const u16* __restrict__ Vf, const float* __restrict__ posb,
            u16* __restrict__ outF){
  __shared__ u16 lK[16384];      // 32 frags x 1KB, fragment order
  __shared__ u16 lV[16384];      // 32 frags x 1KB (16 kc x 2 dblk)
  __shared__ float lPf[3392];    // pos table f32 (x log2e)
  const int bid = blockIdx.x;
  const int hh = bid&7;
  const int tid = threadIdx.x, wid = tid>>6, lane = tid&63;
  const int lr = lane&15, lg = lane>>4;
  const u16* Kb = Kf + (size_t)bid*16384;
  const u16* Vb = Vf + (size_t)bid*16384;
  const u16* Qb = Q  + (size_t)bid*16384;
  #pragma unroll
  for (int r=0;r<4;r++){
    int off = (r*512 + tid)*16;
    gll16((const char*)Kb + off, (char*)lK + off);
    gll16((const char*)Vb + off, (char*)lV + off);
  }
  const float* ptab = posb + (size_t)hh*3376;
  for (int t=tid; t<3375; t+=512) lPf[t] = ptab[t];
  __syncthreads();
  const f32x4 z4 = {0.f,0.f,0.f,0.f};
  const bf16x8 ones = {(short)0x3F80,(short)0x3F80,(short)0x3F80,(short)0x3F80,
                       (short)0x3F80,(short)0x3F80,(short)0x3F80,(short)0x3F80};

  for (int ch=0; ch<4; ++ch){
    const int r0 = wid*64 + ch*16;
    const int q  = r0 + lr;
    // bias index base: idx(nc,v) = Ab - (nc>>2)*225 - (nc&3)*30 - v
    const int Ab = (q>>6)*225 + ((q>>3)&7)*15 + (q&7) + 1687 - (lg>>1)*15 - (lg&1)*4;
    bf16x8 qf = *(const bf16x8*)(Qb + (size_t)q*32 + lg*8);
    f32x4 o0 = z4, o1 = z4, as_ = z4;
    #pragma unroll
    for (int ph=0; ph<2; ++ph){
      // S^T frags for this half: sf[i][v] = S[q][n=(ph*16+i)*16+lg*4+v]  (exp2 domain)
      f32x4 sf[16];
      __builtin_amdgcn_s_setprio(1);
      #pragma unroll
      for (int i=0;i<16;i++){
        int nc = ph*16 + i;
        bf16x8 kf = *(const bf16x8*)&lK[(nc*64 + lane)*8];
        sf[i] = __builtin_amdgcn_mfma_f32_16x16x32_bf16(kf, qf, z4, 0,0,0);
      }
      __builtin_amdgcn_s_setprio(0);
      // P = exp2(S + bias)
      #pragma unroll
      for (int i=0;i<16;i++){
        int nc = ph*16 + i;
        const float* bp = lPf + (Ab - (nc>>2)*225 - (nc&3)*30 - 3);
        sf[i][3] = exp2f(sf[i][3] + bp[0]);
        sf[i][2] = exp2f(sf[i][2] + bp[1]);
        sf[i][1] = exp2f(sf[i][1] + bp[2]);
        sf[i][0] = exp2f(sf[i][0] + bp[3]);
      }
      // PV + ones-MFMA rowsum over this half's 8 kc blocks
      #pragma unroll
      for (int kc=0;kc<8;kc++){
        u32 a0 = pk2(sf[2*kc  ][0], sf[2*kc  ][1]);
        u32 a1 = pk2(sf[2*kc  ][2], sf[2*kc  ][3]);
        u32 b0 = pk2(sf[2*kc+1][0], sf[2*kc+1][1]);
        u32 b1 = pk2(sf[2*kc+1][2], sf[2*kc+1][3]);
        asm("v_permlane32_swap_b32 %0, %1" : "+v"(a0), "+v"(b0));
        asm("v_permlane16_swap_b32 %0, %1" : "+v"(a0), "+v"(b0));  // a0=T0, b0=T2
        asm("v_permlane32_swap_b32 %0, %1" : "+v"(a1), "+v"(b1));
        asm("v_permlane16_swap_b32 %0, %1" : "+v"(a1), "+v"(b1));  // a1=T1, b1=T3
        bf16x8 pf;
        ((u32*)&pf)[0]=a0; ((u32*)&pf)[1]=a1; ((u32*)&pf)[2]=b0; ((u32*)&pf)[3]=b1;
        int kcg = ph*8 + kc;
        bf16x8 v0 = *(const bf16x8*)&lV[(size_t)((kcg*2+0)*64 + lane)*8];
        bf16x8 v1 = *(const bf16x8*)&lV[(size_t)((kcg*2+1)*64 + lane)*8];
        __builtin_amdgcn_s_setprio(1);
        o0  = __builtin_amdgcn_mfma_f32_16x16x32_bf16(pf, v0, o0, 0,0,0);
        o1  = __builtin_amdgcn_mfma_f32_16x16x32_bf16(pf, v1, o1, 0,0,0);
        as_ = __builtin_amdgcn_mfma_f32_16x16x32_bf16(pf, ones, as_, 0,0,0);
        __builtin_amdgcn_s_setprio(0);
      }
    }
    #pragma unroll
    for (int v=0;v<4;v++){
      float inv = 1.0f / as_[v];          // rowsum already in this lane's row slot
      int n = r0 + lg*4 + v;
      size_t base = ((size_t)bid*512 + n)*32;
      outF[base + lr]      = f2b(o0[v]*inv);
      outF[base + 16 + lr] = f2b(o1[v]*inv);
    }
  }
}

// ---------------- host launch ----------------
extern "C" void kernel_launch(void* const* d_in, const int* in_sizes, int n_in,
                              void* d_out, int out_size, void* d_ws, size_t ws_size,
                              hipStream_t stream){
  const float* x      = (const float*)d_in[0];
  const float* y      = (const float*)d_in[1];
  const float* n1_g   = (const float*)d_in[2];
  const float* n1_b   = (const float*)d_in[3];
  const float* qkv_w  = (const float*)d_in[4];
  const float* qkv_b  = (const float*)d_in[5];
  const float* pp_w   = (const float*)d_in[6];
  const float* pp_b   = (const float*)d_in[7];
  const float* p1_lng = (const float*)d_in[8];
  const float* p1_lnb = (const float*)d_in[9];
  const float* p1_w   = (const float*)d_in[10];
  const float* p1_b   = (const float*)d_in[11];
  const float* p2_lng = (const float*)d_in[12];
  const float* p2_lnb = (const float*)d_in[13];
  const float* p2_w   = (const float*)d_in[14];
  const float* p2_b   = (const float*)d_in[15];
  const float* p3_lng = (const float*)d_in[16];
  const float* p3_lnb = (const float*)d_in[17];
  const float* p3_w   = (const float*)d_in[18];
  const float* p3_b   = (const float*)d_in[19];
  const float* proj_w = (const float*)d_in[20];
  const float* proj_b = (const float*)d_in[21];
  const float* n2_g   = (const float*)d_in[22];
  const float* n2_b   = (const float*)d_in[23];
  const float* fc1_w  = (const float*)d_in[24];
  const float* fc1_b  = (const float*)d_in[25];
  const float* fc2_w  = (const float*)d_in[26];
  const float* fc2_b  = (const float*)d_in[27];
  float* out = (float*)d_out;
  char* ws = (char*)d_ws;

  // workspace layout (bytes)
  u16*   qkvT  = (u16*)  (ws + 0);          // [768][256] bf16
  u16*   projT = (u16*)  (ws + 393216);     // [256][256]
  u16*   fc1T  = (u16*)  (ws + 524288);     // [1024][256]
  u16*   fc2T  = (u16*)  (ws + 1048576);    // [256][1024]
  float* posb  = (float*)(ws + 1572864);    // [8][3376] f32 per-head pos tables (x log2e)
  u16*   hbuf  = (u16*)  (ws + 5898240);    // MLP hidden [32768][1024] bf16 (67 MB)
  u16*   Qb    = (u16*)  (ws + 39452672);   // [512 bh][512 n][32 d]   (dead by fc1)
  u16*   Kfb   = (u16*)  (ws + 56229888);   // [512 bh][32 frag][64 lane][8]  (dead by fc1)
  u16*   Vfb   = (u16*)  (ws + 73007104);   // [512 bh][32 frag][64 lane][8]  (dead by proj)
  u16*   attnF = (u16*)  (ws + 89784320);   // [512 bh][512 n][32 d] block-contiguous
  float* xres  = (float*)(ws + 106561536);  // [32768][256] fp32   (end 140,115,968)

  wtrall_k<<<3072,256,0,stream>>>(qkv_w, proj_w, fc1_w, fc2_w, qkvT, projT, fc1T, fc2T);
  posmlp_k<<<14,256,0,stream>>>(pp_w, pp_b,
                                p1_lng,p1_lnb,p1_w,p1_b,
                                p2_lng,p2_lnb,p2_w,p2_b,
                                p3_lng,p3_lnb,p3_w,p3_b, posb);

  GemmP pq; pq.A=nullptr; pq.Af32=x; pq.lng=n1_g; pq.lnb=n1_b;
  pq.Bt=qkvT; pq.K=256; pq.bvec=qkv_b;
  pq.scale=0.17677669529663687f*1.4426950408889634f;  // hd^-0.5 * log2(e)
  pq.add32=nullptr; pq.out32=nullptr; pq.out16=Qb; pq.out16b=nullptr;
  gemmA_k<0,1,2><<<512,512,0,stream>>>(pq);

  GemmP pkv; pkv.A=nullptr; pkv.Af32=y; pkv.lng=nullptr; pkv.lnb=nullptr;
  pkv.Bt=qkvT + 256*256; pkv.K=256; pkv.bvec=qkv_b + 256;
  pkv.scale=1.f; pkv.add32=nullptr; pkv.out32=nullptr; pkv.out16=Kfb; pkv.out16b=Vfb;
  gemmA_k<1,2,4><<<512,512,0,stream>>>(pkv);

  attn_k<<<512,512,0,stream>>>(Qb, Kfb, Vfb, posb, attnF);

  GemmP pp; pp.A=attnF; pp.Af32=nullptr; pp.lng=nullptr; pp.lnb=nullptr;
  pp.Bt=projT; pp.K=256; pp.bvec=proj_b;
  pp.scale=1.f; pp.add32=x; pp.out32=xres; pp.out16=nullptr; pp.out16b=nullptr;
  gemmA_k<2,3,2><<<512,512,0,stream>>>(pp);

  GemmP pf1; pf1.A=nullptr; pf1.Af32=xres; pf1.lng=n2_g; pf1.lnb=n2_b;
  pf1.Bt=fc1T; pf1.K=256; pf1.bvec=fc1_b;
  pf1.scale=1.f; pf1.add32=nullptr; pf1.out32=nullptr; pf1.out16=hbuf; pf1.out16b=nullptr;
  gemmA_k<3,1,8><<<512,512,0,stream>>>(pf1);

  GemmP pf2; pf2.A=hbuf; pf2.Af32=nullptr; pf2.lng=nullptr; pf2.lnb=nullptr;
  pf2.Bt=fc2T; pf2.K=1024; pf2.bvec=fc2_b;
  pf2.scale=1.f; pf2.add32=xres; pf2.out32=out; pf2.out16=nullptr; pf2.out16b=nullptr;
  gemmW_k<<<512,512,0,stream>>>(pf2);
}